// Round 1
// baseline (343.534 us; speedup 1.0000x reference)
//
#include <hip/hip_runtime.h>
#include <math.h>

#define NWIN 7
#define P2 49
#define NB 8
#define NP 392          // NB*P2
#define CDIM 128
#define HH 56
#define PROJC 384
#define HEADS 8
#define HD 16
#define TOPK 4
#define SCALE 0.08838834764831843f   // 128^-0.5

// ---------------- Kernel 1: windowed QKV projection ----------------
// grid = NP*6 (6 tiles of 64 over the 384 output cols), block = 256
// proj layout: [win][t(64)][384]
__global__ __launch_bounds__(256) void k_qkv(const float* __restrict__ x,
    const float* __restrict__ Wqkv, const float* __restrict__ bqkv,
    float* __restrict__ proj)
{
    const int b = blockIdx.x;
    const int win = b / 6, ntile = b % 6;
    const int n = win / P2, p = win % P2;
    const int wy = p / NWIN, wx = p % NWIN;
    __shared__ __align__(16) float xsT[32 * 68];   // [k][t], pad 68
    __shared__ __align__(16) float wts[32 * 68];   // [k][j], pad 68
    const int tid = threadIdx.x;
    const int t0 = (tid >> 4) * 4, j0 = (tid & 15) * 4;
    float acc[4][4];
    #pragma unroll
    for (int jx = 0; jx < 4; ++jx) {
        const float bb = bqkv[ntile * 64 + j0 + jx];
        #pragma unroll
        for (int ti = 0; ti < 4; ++ti) acc[ti][jx] = bb;
    }
    for (int kc = 0; kc < 4; ++kc) {
        #pragma unroll
        for (int i = tid; i < 2048; i += 256) {
            const int k = i >> 6, t = i & 63;
            const int h = wy * 8 + (t >> 3), w = wx * 8 + (t & 7);
            xsT[k * 68 + t] = x[((size_t)(n * CDIM + kc * 32 + k) * HH + h) * HH + w];
            wts[k * 68 + t] = Wqkv[(size_t)(kc * 32 + k) * PROJC + ntile * 64 + t];
        }
        __syncthreads();
        #pragma unroll
        for (int k = 0; k < 32; ++k) {
            const float4 a  = *(const float4*)&xsT[k * 68 + t0];
            const float4 w4 = *(const float4*)&wts[k * 68 + j0];
            const float av[4] = {a.x, a.y, a.z, a.w};
            const float wv[4] = {w4.x, w4.y, w4.z, w4.w};
            #pragma unroll
            for (int ti = 0; ti < 4; ++ti)
                #pragma unroll
                for (int jx = 0; jx < 4; ++jx)
                    acc[ti][jx] = fmaf(av[ti], wv[jx], acc[ti][jx]);
        }
        __syncthreads();
    }
    #pragma unroll
    for (int ti = 0; ti < 4; ++ti) {
        float4 v = make_float4(acc[ti][0], acc[ti][1], acc[ti][2], acc[ti][3]);
        *(float4*)&proj[(size_t)(win * 64 + t0 + ti) * PROJC + ntile * 64 + j0] = v;
    }
}

// ---------------- Kernel 2: window means ----------------
// grid = NP, block = 128
__global__ __launch_bounds__(128) void k_means(const float* __restrict__ proj,
    float* __restrict__ qwin, float* __restrict__ kwin)
{
    const int win = blockIdx.x;
    const int c = threadIdx.x;
    float sq = 0.f, sk = 0.f;
    for (int t = 0; t < 64; ++t) {
        const float* row = proj + (size_t)(win * 64 + t) * PROJC;
        sq += row[c];
        sk += row[128 + c];
    }
    qwin[(size_t)win * 128 + c] = sq * (1.f / 64.f);
    kwin[(size_t)win * 128 + c] = sk * (1.f / 64.f);
}

// ---------------- Kernel 3: routing top-4 ----------------
// grid = NP, block = 64 (one wave). Only the SET of top-4 matters (softmax
// attention is permutation-invariant over keys); tie-break = lower index
// to match jax.lax.top_k.
__global__ __launch_bounds__(64) void k_route(const float* __restrict__ qwin,
    const float* __restrict__ kwin, int* __restrict__ ridx)
{
    const int win = blockIdx.x;
    const int n = win / P2;
    const int lane = threadIdx.x;
    float v = -INFINITY;
    if (lane < P2) {
        const float* qr = qwin + (size_t)win * 128;
        const float* kr = kwin + ((size_t)n * P2 + lane) * 128;
        float s = 0.f;
        for (int c = 0; c < 128; ++c) s = fmaf(qr[c], kr[c], s);
        v = s;  // SCALE omitted: monotonic, doesn't change top-k set/order
    }
    #pragma unroll
    for (int sel = 0; sel < TOPK; ++sel) {
        float mv = v; int mi = lane;
        #pragma unroll
        for (int off = 32; off >= 1; off >>= 1) {
            const float ov = __shfl_xor(mv, off);
            const int   oi = __shfl_xor(mi, off);
            if (ov > mv || (ov == mv && oi < mi)) { mv = ov; mi = oi; }
        }
        if (lane == 0) ridx[win * 4 + sel] = mi;
        if (lane == mi) v = -INFINITY;
    }
}

// ---------------- Kernel 4: gathered attention ----------------
// grid = (NP, HEADS), block = 256. thread = (q_row = tid>>2, key_chunk = tid&3)
// LDS layout [kk][chunk][16] -> chunk*16 mod 32 = {0,16} => 2-way (free)
__global__ __launch_bounds__(256) void k_attn(const float* __restrict__ proj,
    const int* __restrict__ ridx, float* __restrict__ obuf)
{
    const int win = blockIdx.x, m = blockIdx.y;
    const int n = win / P2;
    __shared__ __align__(16) float kl[256 * 16];
    __shared__ __align__(16) float vl[256 * 16];
    __shared__ __align__(16) float ql[64 * 16];
    __shared__ int widx[4];
    const int tid = threadIdx.x;
    if (tid < 4) widx[tid] = ridx[win * 4 + tid];
    __syncthreads();
    for (int i = tid; i < 4096; i += 256) {
        const int pix = i >> 4, d = i & 15;
        const int chunk = pix >> 6, kk = pix & 63;
        const size_t src = ((size_t)(n * P2 + widx[chunk]) * 64 + kk) * PROJC;
        kl[(kk * 4 + chunk) * 16 + d] = proj[src + 128 + m * 16 + d];
        vl[(kk * 4 + chunk) * 16 + d] = proj[src + 256 + m * 16 + d];
    }
    for (int i = tid; i < 1024; i += 256) {
        const int t = i >> 4, d = i & 15;
        ql[i] = proj[((size_t)win * 64 + t) * PROJC + m * 16 + d];
    }
    __syncthreads();

    const int row = tid >> 2, chunk = tid & 3;
    const float4 q0 = *(const float4*)&ql[row * 16 + 0];
    const float4 q1 = *(const float4*)&ql[row * 16 + 4];
    const float4 q2 = *(const float4*)&ql[row * 16 + 8];
    const float4 q3 = *(const float4*)&ql[row * 16 + 12];

    float s[64];
    #pragma unroll
    for (int kk = 0; kk < 64; ++kk) {
        const int base = (kk * 4 + chunk) * 16;
        const float4 k0 = *(const float4*)&kl[base + 0];
        const float4 k1 = *(const float4*)&kl[base + 4];
        const float4 k2 = *(const float4*)&kl[base + 8];
        const float4 k3 = *(const float4*)&kl[base + 12];
        float d0 = q0.x * k0.x + q0.y * k0.y + q0.z * k0.z + q0.w * k0.w;
        d0 += q1.x * k1.x + q1.y * k1.y + q1.z * k1.z + q1.w * k1.w;
        d0 += q2.x * k2.x + q2.y * k2.y + q2.z * k2.z + q2.w * k2.w;
        d0 += q3.x * k3.x + q3.y * k3.y + q3.z * k3.z + q3.w * k3.w;
        s[kk] = d0 * SCALE;
    }
    float mx = -INFINITY;
    #pragma unroll
    for (int kk = 0; kk < 64; ++kk) mx = fmaxf(mx, s[kk]);
    mx = fmaxf(mx, __shfl_xor(mx, 1));
    mx = fmaxf(mx, __shfl_xor(mx, 2));
    float sum = 0.f;
    #pragma unroll
    for (int kk = 0; kk < 64; ++kk) { s[kk] = __expf(s[kk] - mx); sum += s[kk]; }
    sum += __shfl_xor(sum, 1);
    sum += __shfl_xor(sum, 2);
    const float inv = 1.f / sum;

    float o[16];
    #pragma unroll
    for (int d = 0; d < 16; ++d) o[d] = 0.f;
    #pragma unroll
    for (int kk = 0; kk < 64; ++kk) {
        const int base = (kk * 4 + chunk) * 16;
        const float pr = s[kk];
        const float4 v0 = *(const float4*)&vl[base + 0];
        const float4 v1 = *(const float4*)&vl[base + 4];
        const float4 v2 = *(const float4*)&vl[base + 8];
        const float4 v3 = *(const float4*)&vl[base + 12];
        o[0]  = fmaf(pr, v0.x, o[0]);  o[1]  = fmaf(pr, v0.y, o[1]);
        o[2]  = fmaf(pr, v0.z, o[2]);  o[3]  = fmaf(pr, v0.w, o[3]);
        o[4]  = fmaf(pr, v1.x, o[4]);  o[5]  = fmaf(pr, v1.y, o[5]);
        o[6]  = fmaf(pr, v1.z, o[6]);  o[7]  = fmaf(pr, v1.w, o[7]);
        o[8]  = fmaf(pr, v2.x, o[8]);  o[9]  = fmaf(pr, v2.y, o[9]);
        o[10] = fmaf(pr, v2.z, o[10]); o[11] = fmaf(pr, v2.w, o[11]);
        o[12] = fmaf(pr, v3.x, o[12]); o[13] = fmaf(pr, v3.y, o[13]);
        o[14] = fmaf(pr, v3.z, o[14]); o[15] = fmaf(pr, v3.w, o[15]);
    }
    #pragma unroll
    for (int d = 0; d < 16; ++d) {
        o[d] += __shfl_xor(o[d], 1);
        o[d] += __shfl_xor(o[d], 2);
    }
    if (chunk == 0) {
        float* dst = obuf + ((size_t)win * 64 + row) * 128 + m * 16;
        *(float4*)&dst[0]  = make_float4(o[0] * inv,  o[1] * inv,  o[2] * inv,  o[3] * inv);
        *(float4*)&dst[4]  = make_float4(o[4] * inv,  o[5] * inv,  o[6] * inv,  o[7] * inv);
        *(float4*)&dst[8]  = make_float4(o[8] * inv,  o[9] * inv,  o[10] * inv, o[11] * inv);
        *(float4*)&dst[12] = make_float4(o[12] * inv, o[13] * inv, o[14] * inv, o[15] * inv);
    }
}

// ---------------- Kernel 5: lepe conv + output projection ----------------
// grid = (NP, 2), block = 256. Phase 1 builds sT[c][t] = o + lepe (both
// y-blocks duplicate it, cheap); phase 2 = 64x64 GEMM tile over K=128.
__global__ __launch_bounds__(256) void k_out(const float* __restrict__ proj,
    const float* __restrict__ obuf, const float* __restrict__ lw,
    const float* __restrict__ lb, const float* __restrict__ Wo,
    const float* __restrict__ bo, float* __restrict__ out)
{
    const int win = blockIdx.x, jh = blockIdx.y;
    const int n = win / P2, p = win % P2;
    const int wy = p / NWIN, wx = p % NWIN;
    __shared__ __align__(16) float sT[128 * 68];   // [c][t] pad 68 (34.8 KB)
    __shared__ __align__(16) float wts[32 * 68];   // [k][j] chunked (8.7 KB)
    const int tid = threadIdx.x;

    for (int i = tid; i < 8192; i += 256) {
        const int c = i & 127, t = i >> 7;
        const int h = wy * 8 + (t >> 3), w = wx * 8 + (t & 7);
        float a = lb[c];
        #pragma unroll
        for (int ky = 0; ky < 3; ++ky) {
            const int h2 = h + ky - 1;
            if (h2 < 0 || h2 >= HH) continue;
            #pragma unroll
            for (int kx = 0; kx < 3; ++kx) {
                const int w2 = w + kx - 1;
                if (w2 < 0 || w2 >= HH) continue;
                const int pp = (h2 >> 3) * NWIN + (w2 >> 3);
                const int t2 = (h2 & 7) * 8 + (w2 & 7);
                a = fmaf(proj[((size_t)(n * P2 + pp) * 64 + t2) * PROJC + 256 + c],
                         lw[c * 9 + ky * 3 + kx], a);
            }
        }
        a += obuf[((size_t)win * 64 + t) * 128 + c];
        sT[c * 68 + t] = a;
    }
    __syncthreads();

    const int t0 = (tid >> 4) * 4, j0 = (tid & 15) * 4;
    float acc[4][4];
    #pragma unroll
    for (int jx = 0; jx < 4; ++jx) {
        const float bb = bo[jh * 64 + j0 + jx];
        #pragma unroll
        for (int ti = 0; ti < 4; ++ti) acc[ti][jx] = bb;
    }
    for (int kc = 0; kc < 4; ++kc) {
        #pragma unroll
        for (int i = tid; i < 2048; i += 256) {
            const int k = i >> 6, j = i & 63;
            wts[k * 68 + j] = Wo[(size_t)(kc * 32 + k) * 128 + jh * 64 + j];
        }
        __syncthreads();
        #pragma unroll
        for (int k = 0; k < 32; ++k) {
            const float4 a  = *(const float4*)&sT[(kc * 32 + k) * 68 + t0];
            const float4 w4 = *(const float4*)&wts[k * 68 + j0];
            const float av[4] = {a.x, a.y, a.z, a.w};
            const float wv[4] = {w4.x, w4.y, w4.z, w4.w};
            #pragma unroll
            for (int ti = 0; ti < 4; ++ti)
                #pragma unroll
                for (int jx = 0; jx < 4; ++jx)
                    acc[ti][jx] = fmaf(av[ti], wv[jx], acc[ti][jx]);
        }
        __syncthreads();
    }
    // t0..t0+3 lie in one image row => float4 store along w
    const int iy = t0 >> 3, ix0 = t0 & 7;
    const int h = wy * 8 + iy, w0 = wx * 8 + ix0;
    #pragma unroll
    for (int jx = 0; jx < 4; ++jx) {
        const int cout = jh * 64 + j0 + jx;
        float4 v = make_float4(acc[0][jx], acc[1][jx], acc[2][jx], acc[3][jx]);
        *(float4*)&out[(((size_t)n * CDIM + cout) * HH + h) * HH + w0] = v;
    }
}

extern "C" void kernel_launch(void* const* d_in, const int* in_sizes, int n_in,
                              void* d_out, int out_size, void* d_ws, size_t ws_size,
                              hipStream_t stream)
{
    const float* x    = (const float*)d_in[0];
    const float* Wqkv = (const float*)d_in[1];
    const float* bqkv = (const float*)d_in[2];
    const float* lw   = (const float*)d_in[3];
    const float* lb   = (const float*)d_in[4];
    const float* Wo   = (const float*)d_in[5];
    const float* bo   = (const float*)d_in[6];
    float* out = (float*)d_out;

    float* ws   = (float*)d_ws;
    float* proj = ws;                                   // NP*64*384
    float* qwin = proj + (size_t)NP * 64 * PROJC;       // NP*128
    float* kwin = qwin + (size_t)NP * 128;              // NP*128
    int*   ridx = (int*)(kwin + (size_t)NP * 128);      // NP*4 ints
    float* obuf = (float*)(ridx + NP * 4);              // NP*64*128

    k_qkv  <<<dim3(NP * 6), 256, 0, stream>>>(x, Wqkv, bqkv, proj);
    k_means<<<dim3(NP), 128, 0, stream>>>(proj, qwin, kwin);
    k_route<<<dim3(NP), 64, 0, stream>>>(qwin, kwin, ridx);
    k_attn <<<dim3(NP, HEADS), 256, 0, stream>>>(proj, ridx, obuf);
    k_out  <<<dim3(NP, 2), 256, 0, stream>>>(proj, obuf, lw, lb, Wo, bo, out);
}

// Round 2
// 213.812 us; speedup vs baseline: 1.6067x; 1.6067x over previous
//
#include <hip/hip_runtime.h>
#include <math.h>

#define NWIN 7
#define P2 49
#define NB 8
#define NP 392          // NB*P2
#define CDIM 128
#define HH 56
#define PROJC 384
#define HEADS 8
#define HD 16
#define TOPK 4
#define SCALE 0.08838834764831843f   // 128^-0.5

// ---------------- Kernel 1: windowed QKV projection ----------------
// grid = NP*6 (6 tiles of 64 over the 384 output cols), block = 256
// proj layout: [win][t(64)][384]
__global__ __launch_bounds__(256) void k_qkv(const float* __restrict__ x,
    const float* __restrict__ Wqkv, const float* __restrict__ bqkv,
    float* __restrict__ proj)
{
    const int b = blockIdx.x;
    const int win = b / 6, ntile = b % 6;
    const int n = win / P2, p = win % P2;
    const int wy = p / NWIN, wx = p % NWIN;
    __shared__ __align__(16) float xsT[32 * 68];   // [k][t], pad 68
    __shared__ __align__(16) float wts[32 * 68];   // [k][j], pad 68
    const int tid = threadIdx.x;
    const int t0 = (tid >> 4) * 4, j0 = (tid & 15) * 4;
    float acc[4][4];
    #pragma unroll
    for (int jx = 0; jx < 4; ++jx) {
        const float bb = bqkv[ntile * 64 + j0 + jx];
        #pragma unroll
        for (int ti = 0; ti < 4; ++ti) acc[ti][jx] = bb;
    }
    for (int kc = 0; kc < 4; ++kc) {
        #pragma unroll
        for (int i = tid; i < 2048; i += 256) {
            const int k = i >> 6, t = i & 63;
            const int h = wy * 8 + (t >> 3), w = wx * 8 + (t & 7);
            xsT[k * 68 + t] = x[((size_t)(n * CDIM + kc * 32 + k) * HH + h) * HH + w];
            wts[k * 68 + t] = Wqkv[(size_t)(kc * 32 + k) * PROJC + ntile * 64 + t];
        }
        __syncthreads();
        #pragma unroll
        for (int k = 0; k < 32; ++k) {
            const float4 a  = *(const float4*)&xsT[k * 68 + t0];
            const float4 w4 = *(const float4*)&wts[k * 68 + j0];
            const float av[4] = {a.x, a.y, a.z, a.w};
            const float wv[4] = {w4.x, w4.y, w4.z, w4.w};
            #pragma unroll
            for (int ti = 0; ti < 4; ++ti)
                #pragma unroll
                for (int jx = 0; jx < 4; ++jx)
                    acc[ti][jx] = fmaf(av[ti], wv[jx], acc[ti][jx]);
        }
        __syncthreads();
    }
    #pragma unroll
    for (int ti = 0; ti < 4; ++ti) {
        float4 v = make_float4(acc[ti][0], acc[ti][1], acc[ti][2], acc[ti][3]);
        *(float4*)&proj[(size_t)(win * 64 + t0 + ti) * PROJC + ntile * 64 + j0] = v;
    }
}

// ---------------- Kernel 2: window means ----------------
__global__ __launch_bounds__(128) void k_means(const float* __restrict__ proj,
    float* __restrict__ qwin, float* __restrict__ kwin)
{
    const int win = blockIdx.x;
    const int c = threadIdx.x;
    float sq = 0.f, sk = 0.f;
    for (int t = 0; t < 64; ++t) {
        const float* row = proj + (size_t)(win * 64 + t) * PROJC;
        sq += row[c];
        sk += row[128 + c];
    }
    qwin[(size_t)win * 128 + c] = sq * (1.f / 64.f);
    kwin[(size_t)win * 128 + c] = sk * (1.f / 64.f);
}

// ---------------- Kernel 3: routing top-4 ----------------
__global__ __launch_bounds__(64) void k_route(const float* __restrict__ qwin,
    const float* __restrict__ kwin, int* __restrict__ ridx)
{
    const int win = blockIdx.x;
    const int n = win / P2;
    const int lane = threadIdx.x;
    float v = -INFINITY;
    if (lane < P2) {
        const float* qr = qwin + (size_t)win * 128;
        const float* kr = kwin + ((size_t)n * P2 + lane) * 128;
        float s = 0.f;
        for (int c = 0; c < 128; ++c) s = fmaf(qr[c], kr[c], s);
        v = s;
    }
    #pragma unroll
    for (int sel = 0; sel < TOPK; ++sel) {
        float mv = v; int mi = lane;
        #pragma unroll
        for (int off = 32; off >= 1; off >>= 1) {
            const float ov = __shfl_xor(mv, off);
            const int   oi = __shfl_xor(mi, off);
            if (ov > mv || (ov == mv && oi < mi)) { mv = ov; mi = oi; }
        }
        if (lane == 0) ridx[win * 4 + sel] = mi;
        if (lane == mi) v = -INFINITY;
    }
}

// ---------------- Kernel 4: gathered attention ----------------
__global__ __launch_bounds__(256) void k_attn(const float* __restrict__ proj,
    const int* __restrict__ ridx, float* __restrict__ obuf)
{
    const int win = blockIdx.x, m = blockIdx.y;
    const int n = win / P2;
    __shared__ __align__(16) float kl[256 * 16];
    __shared__ __align__(16) float vl[256 * 16];
    __shared__ __align__(16) float ql[64 * 16];
    __shared__ int widx[4];
    const int tid = threadIdx.x;
    if (tid < 4) widx[tid] = ridx[win * 4 + tid];
    __syncthreads();
    for (int i = tid; i < 4096; i += 256) {
        const int pix = i >> 4, d = i & 15;
        const int chunk = pix >> 6, kk = pix & 63;
        const size_t src = ((size_t)(n * P2 + widx[chunk]) * 64 + kk) * PROJC;
        kl[(kk * 4 + chunk) * 16 + d] = proj[src + 128 + m * 16 + d];
        vl[(kk * 4 + chunk) * 16 + d] = proj[src + 256 + m * 16 + d];
    }
    for (int i = tid; i < 1024; i += 256) {
        const int t = i >> 4, d = i & 15;
        ql[i] = proj[((size_t)win * 64 + t) * PROJC + m * 16 + d];
    }
    __syncthreads();

    const int row = tid >> 2, chunk = tid & 3;
    const float4 q0 = *(const float4*)&ql[row * 16 + 0];
    const float4 q1 = *(const float4*)&ql[row * 16 + 4];
    const float4 q2 = *(const float4*)&ql[row * 16 + 8];
    const float4 q3 = *(const float4*)&ql[row * 16 + 12];

    float s[64];
    #pragma unroll
    for (int kk = 0; kk < 64; ++kk) {
        const int base = (kk * 4 + chunk) * 16;
        const float4 k0 = *(const float4*)&kl[base + 0];
        const float4 k1 = *(const float4*)&kl[base + 4];
        const float4 k2 = *(const float4*)&kl[base + 8];
        const float4 k3 = *(const float4*)&kl[base + 12];
        float d0 = q0.x * k0.x + q0.y * k0.y + q0.z * k0.z + q0.w * k0.w;
        d0 += q1.x * k1.x + q1.y * k1.y + q1.z * k1.z + q1.w * k1.w;
        d0 += q2.x * k2.x + q2.y * k2.y + q2.z * k2.z + q2.w * k2.w;
        d0 += q3.x * k3.x + q3.y * k3.y + q3.z * k3.z + q3.w * k3.w;
        s[kk] = d0 * SCALE;
    }
    float mx = -INFINITY;
    #pragma unroll
    for (int kk = 0; kk < 64; ++kk) mx = fmaxf(mx, s[kk]);
    mx = fmaxf(mx, __shfl_xor(mx, 1));
    mx = fmaxf(mx, __shfl_xor(mx, 2));
    float sum = 0.f;
    #pragma unroll
    for (int kk = 0; kk < 64; ++kk) { s[kk] = __expf(s[kk] - mx); sum += s[kk]; }
    sum += __shfl_xor(sum, 1);
    sum += __shfl_xor(sum, 2);
    const float inv = 1.f / sum;

    float o[16];
    #pragma unroll
    for (int d = 0; d < 16; ++d) o[d] = 0.f;
    #pragma unroll
    for (int kk = 0; kk < 64; ++kk) {
        const int base = (kk * 4 + chunk) * 16;
        const float pr = s[kk];
        const float4 v0 = *(const float4*)&vl[base + 0];
        const float4 v1 = *(const float4*)&vl[base + 4];
        const float4 v2 = *(const float4*)&vl[base + 8];
        const float4 v3 = *(const float4*)&vl[base + 12];
        o[0]  = fmaf(pr, v0.x, o[0]);  o[1]  = fmaf(pr, v0.y, o[1]);
        o[2]  = fmaf(pr, v0.z, o[2]);  o[3]  = fmaf(pr, v0.w, o[3]);
        o[4]  = fmaf(pr, v1.x, o[4]);  o[5]  = fmaf(pr, v1.y, o[5]);
        o[6]  = fmaf(pr, v1.z, o[6]);  o[7]  = fmaf(pr, v1.w, o[7]);
        o[8]  = fmaf(pr, v2.x, o[8]);  o[9]  = fmaf(pr, v2.y, o[9]);
        o[10] = fmaf(pr, v2.z, o[10]); o[11] = fmaf(pr, v2.w, o[11]);
        o[12] = fmaf(pr, v3.x, o[12]); o[13] = fmaf(pr, v3.y, o[13]);
        o[14] = fmaf(pr, v3.z, o[14]); o[15] = fmaf(pr, v3.w, o[15]);
    }
    #pragma unroll
    for (int d = 0; d < 16; ++d) {
        o[d] += __shfl_xor(o[d], 1);
        o[d] += __shfl_xor(o[d], 2);
    }
    if (chunk == 0) {
        float* dst = obuf + ((size_t)win * 64 + row) * 128 + m * 16;
        *(float4*)&dst[0]  = make_float4(o[0] * inv,  o[1] * inv,  o[2] * inv,  o[3] * inv);
        *(float4*)&dst[4]  = make_float4(o[4] * inv,  o[5] * inv,  o[6] * inv,  o[7] * inv);
        *(float4*)&dst[8]  = make_float4(o[8] * inv,  o[9] * inv,  o[10] * inv, o[11] * inv);
        *(float4*)&dst[12] = make_float4(o[12] * inv, o[13] * inv, o[14] * inv, o[15] * inv);
    }
}

// ---------------- Kernel 5a: branchless lepe stencil, obuf += lepe ----------
// grid = (392 = 14 h-tiles * 28 w-tiles, 8 images), block = 256 (128 c x 2 w)
// Each thread: 4 vertically adjacent pixels -> 6x3 shared neighborhood,
// all 18 v-loads unconditional (clamped addr, weight zeroed by mask).
__global__ __launch_bounds__(256) void k_lepe(const float* __restrict__ proj,
    const float* __restrict__ lw, const float* __restrict__ lb,
    float* __restrict__ obuf)
{
    const int n = blockIdx.y;
    const int ht = blockIdx.x / 28, wt = blockIdx.x % 28;
    const int tid = threadIdx.x;
    const int c = tid & 127, wi = tid >> 7;
    const int h0 = ht * 4;
    const int w = wt * 2 + wi;

    float lw9[9];
    #pragma unroll
    for (int t = 0; t < 9; ++t) lw9[t] = lw[c * 9 + t];
    const float bias = lb[c];

    int wcl[3]; bool wv[3];
    #pragma unroll
    for (int kx = 0; kx < 3; ++kx) {
        const int wc = w + kx - 1;
        wv[kx] = (wc >= 0) && (wc < HH);
        wcl[kx] = min(max(wc, 0), HH - 1);
    }
    bool rv[6]; int rcl[6];
    #pragma unroll
    for (int r = 0; r < 6; ++r) {
        const int hr = h0 + r - 1;
        rv[r] = (hr >= 0) && (hr < HH);
        rcl[r] = min(max(hr, 0), HH - 1);
    }
    // 18 unconditional loads (clamped addresses), issued as one batch
    float val[6][3];
    #pragma unroll
    for (int r = 0; r < 6; ++r) {
        #pragma unroll
        for (int kx = 0; kx < 3; ++kx) {
            const int hr = rcl[r], wc = wcl[kx];
            const int pp = (hr >> 3) * NWIN + (wc >> 3);
            const int t2 = (hr & 7) * 8 + (wc & 7);
            val[r][kx] = proj[((size_t)(n * P2 + pp) * 64 + t2) * PROJC + 256 + c];
        }
    }
    #pragma unroll
    for (int hi = 0; hi < 4; ++hi) {
        float a = bias;
        #pragma unroll
        for (int ky = 0; ky < 3; ++ky) {
            #pragma unroll
            for (int kx = 0; kx < 3; ++kx) {
                const float wgt = (rv[hi + ky] && wv[kx]) ? lw9[ky * 3 + kx] : 0.f;
                a = fmaf(val[hi + ky][kx], wgt, a);
            }
        }
        const int h = h0 + hi;
        const int win = (h >> 3) * NWIN + (w >> 3);
        const int t = (h & 7) * 8 + (w & 7);
        const size_t idx = (((size_t)n * P2 + win) * 64 + t) * 128 + c;
        obuf[idx] += a;
    }
}

// ---------------- Kernel 5b: pure output GEMM ----------------
// grid = (NP, 2), block = 256. 64 tokens x 64 cols, K chunked by 32.
// LDS: sA [64][36] row-major (9.2KB) + sW [32][68] (8.7KB) -> 8 blocks/CU.
__global__ __launch_bounds__(256) void k_out(const float* __restrict__ obuf,
    const float* __restrict__ Wo, const float* __restrict__ bo,
    float* __restrict__ out)
{
    const int win = blockIdx.x, jh = blockIdx.y;
    const int n = win / P2, p = win % P2;
    const int wy = p / NWIN, wx = p % NWIN;
    __shared__ __align__(16) float sA[64 * 36];
    __shared__ __align__(16) float sW[32 * 68];
    const int tid = threadIdx.x;
    const int t0 = (tid >> 4) * 4, j0 = (tid & 15) * 4;

    float acc[4][4];
    #pragma unroll
    for (int jx = 0; jx < 4; ++jx) {
        const float bb = bo[jh * 64 + j0 + jx];
        #pragma unroll
        for (int ti = 0; ti < 4; ++ti) acc[ti][jx] = bb;
    }
    for (int kc = 0; kc < 4; ++kc) {
        {   // A chunk: 64 tokens x 32 k  (512 float4 loads, 2/thread)
            #pragma unroll
            for (int i = tid; i < 512; i += 256) {
                const int t = i >> 3, c4 = i & 7;
                const float4 v = *(const float4*)&obuf[((size_t)win * 64 + t) * 128 + kc * 32 + c4 * 4];
                *(float4*)&sA[t * 36 + c4 * 4] = v;
            }
            // W chunk: 32 k x 64 j
            #pragma unroll
            for (int i = tid; i < 2048; i += 256) {
                const int k = i >> 6, j = i & 63;
                sW[k * 68 + j] = Wo[(size_t)(kc * 32 + k) * 128 + jh * 64 + j];
            }
        }
        __syncthreads();
        #pragma unroll
        for (int k = 0; k < 32; ++k) {
            const float4 w4 = *(const float4*)&sW[k * 68 + j0];
            const float wv[4] = {w4.x, w4.y, w4.z, w4.w};
            float av[4];
            #pragma unroll
            for (int ti = 0; ti < 4; ++ti) av[ti] = sA[(t0 + ti) * 36 + k];
            #pragma unroll
            for (int ti = 0; ti < 4; ++ti)
                #pragma unroll
                for (int jx = 0; jx < 4; ++jx)
                    acc[ti][jx] = fmaf(av[ti], wv[jx], acc[ti][jx]);
        }
        __syncthreads();
    }
    const int iy = t0 >> 3, ix0 = t0 & 7;
    const int h = wy * 8 + iy, w0 = wx * 8 + ix0;
    #pragma unroll
    for (int jx = 0; jx < 4; ++jx) {
        const int cout = jh * 64 + j0 + jx;
        float4 v = make_float4(acc[0][jx], acc[1][jx], acc[2][jx], acc[3][jx]);
        *(float4*)&out[(((size_t)n * CDIM + cout) * HH + h) * HH + w0] = v;
    }
}

extern "C" void kernel_launch(void* const* d_in, const int* in_sizes, int n_in,
                              void* d_out, int out_size, void* d_ws, size_t ws_size,
                              hipStream_t stream)
{
    const float* x    = (const float*)d_in[0];
    const float* Wqkv = (const float*)d_in[1];
    const float* bqkv = (const float*)d_in[2];
    const float* lw   = (const float*)d_in[3];
    const float* lb   = (const float*)d_in[4];
    const float* Wo   = (const float*)d_in[5];
    const float* bo   = (const float*)d_in[6];
    float* out = (float*)d_out;

    float* ws   = (float*)d_ws;
    float* proj = ws;                                   // NP*64*384
    float* qwin = proj + (size_t)NP * 64 * PROJC;       // NP*128
    float* kwin = qwin + (size_t)NP * 128;              // NP*128
    int*   ridx = (int*)(kwin + (size_t)NP * 128);      // NP*4 ints
    float* obuf = (float*)(ridx + NP * 4);              // NP*64*128

    k_qkv  <<<dim3(NP * 6), 256, 0, stream>>>(x, Wqkv, bqkv, proj);
    k_means<<<dim3(NP), 128, 0, stream>>>(proj, qwin, kwin);
    k_route<<<dim3(NP), 64, 0, stream>>>(qwin, kwin, ridx);
    k_attn <<<dim3(NP, HEADS), 256, 0, stream>>>(proj, ridx, obuf);
    k_lepe <<<dim3(392, NB), 256, 0, stream>>>(proj, lw, lb, obuf);
    k_out  <<<dim3(NP, 2), 256, 0, stream>>>(obuf, Wo, bo, out);
}

// Round 5
// 134.656 us; speedup vs baseline: 2.5512x; 1.5878x over previous
//
#include <hip/hip_runtime.h>
#include <math.h>

#define NWIN 7
#define P2 49
#define NB 8
#define NP 392          // NB*P2
#define CDIM 128
#define HH 56
#define PROJC 384
#define HEADS 8
#define HD 16
#define TOPK 4
#define SCALE 0.08838834764831843f   // 128^-0.5

typedef __attribute__((ext_vector_type(4))) float f4;
typedef __attribute__((ext_vector_type(4))) short v4s;

// gfx950 v_mfma_f32_16x16x16_bf16 (A/B = 2 VGPRs = 4 bf16), builtin carries the
// CDNA2-lineage "_1k" name. Single known-good name, no __has_builtin dispatch.
#define MFMA16(a,b,c) __builtin_amdgcn_mfma_f32_16x16x16bf16_1k(a,b,c,0,0,0)

// float -> bf16 round-to-nearest-even, pure integer ops (no inline asm: m240
// says hand-written cvt_pk asm is both slower and a hazard risk).
__device__ inline short f2bf(float x) {
    union { float f; unsigned u; } v; v.f = x;
    const unsigned r = v.u + 0x7FFFu + ((v.u >> 16) & 1u);
    return (short)(r >> 16);
}
__device__ inline v4s mk4(float a, float b, float c, float d) {
    v4s r;
    r[0] = f2bf(a); r[1] = f2bf(b); r[2] = f2bf(c); r[3] = f2bf(d);
    return r;
}

// ---------------- Kernel 1: windowed QKV projection ----------------
// grid = NP*6 (6 tiles of 64 over the 384 output cols), block = 256
// proj layout: [win][t(64)][384]
__global__ __launch_bounds__(256) void k_qkv(const float* __restrict__ x,
    const float* __restrict__ Wqkv, const float* __restrict__ bqkv,
    float* __restrict__ proj)
{
    const int b = blockIdx.x;
    const int win = b / 6, ntile = b % 6;
    const int n = win / P2, p = win % P2;
    const int wy = p / NWIN, wx = p % NWIN;
    __shared__ __align__(16) float xsT[32 * 68];   // [k][t], pad 68
    __shared__ __align__(16) float wts[32 * 68];   // [k][j], pad 68
    const int tid = threadIdx.x;
    const int t0 = (tid >> 4) * 4, j0 = (tid & 15) * 4;
    float acc[4][4];
    #pragma unroll
    for (int jx = 0; jx < 4; ++jx) {
        const float bb = bqkv[ntile * 64 + j0 + jx];
        #pragma unroll
        for (int ti = 0; ti < 4; ++ti) acc[ti][jx] = bb;
    }
    for (int kc = 0; kc < 4; ++kc) {
        #pragma unroll
        for (int i = tid; i < 2048; i += 256) {
            const int k = i >> 6, t = i & 63;
            const int h = wy * 8 + (t >> 3), w = wx * 8 + (t & 7);
            xsT[k * 68 + t] = x[((size_t)(n * CDIM + kc * 32 + k) * HH + h) * HH + w];
            wts[k * 68 + t] = Wqkv[(size_t)(kc * 32 + k) * PROJC + ntile * 64 + t];
        }
        __syncthreads();
        #pragma unroll
        for (int k = 0; k < 32; ++k) {
            const float4 a  = *(const float4*)&xsT[k * 68 + t0];
            const float4 w4 = *(const float4*)&wts[k * 68 + j0];
            const float av[4] = {a.x, a.y, a.z, a.w};
            const float wv[4] = {w4.x, w4.y, w4.z, w4.w};
            #pragma unroll
            for (int ti = 0; ti < 4; ++ti)
                #pragma unroll
                for (int jx = 0; jx < 4; ++jx)
                    acc[ti][jx] = fmaf(av[ti], wv[jx], acc[ti][jx]);
        }
        __syncthreads();
    }
    #pragma unroll
    for (int ti = 0; ti < 4; ++ti) {
        float4 v = make_float4(acc[ti][0], acc[ti][1], acc[ti][2], acc[ti][3]);
        *(float4*)&proj[(size_t)(win * 64 + t0 + ti) * PROJC + ntile * 64 + j0] = v;
    }
}

// ---------------- Kernel 2: window means ----------------
__global__ __launch_bounds__(128) void k_means(const float* __restrict__ proj,
    float* __restrict__ qwin, float* __restrict__ kwin)
{
    const int win = blockIdx.x;
    const int c = threadIdx.x;
    float sq = 0.f, sk = 0.f;
    for (int t = 0; t < 64; ++t) {
        const float* row = proj + (size_t)(win * 64 + t) * PROJC;
        sq += row[c];
        sk += row[128 + c];
    }
    qwin[(size_t)win * 128 + c] = sq * (1.f / 64.f);
    kwin[(size_t)win * 128 + c] = sk * (1.f / 64.f);
}

// ---------------- Kernel 3: routing top-4 ----------------
__global__ __launch_bounds__(64) void k_route(const float* __restrict__ qwin,
    const float* __restrict__ kwin, int* __restrict__ ridx)
{
    const int win = blockIdx.x;
    const int n = win / P2;
    const int lane = threadIdx.x;
    float v = -INFINITY;
    if (lane < P2) {
        const float* qr = qwin + (size_t)win * 128;
        const float* kr = kwin + ((size_t)n * P2 + lane) * 128;
        float s = 0.f;
        for (int c = 0; c < 128; ++c) s = fmaf(qr[c], kr[c], s);
        v = s;
    }
    #pragma unroll
    for (int sel = 0; sel < TOPK; ++sel) {
        float mv = v; int mi = lane;
        #pragma unroll
        for (int off = 32; off >= 1; off >>= 1) {
            const float ov = __shfl_xor(mv, off);
            const int   oi = __shfl_xor(mi, off);
            if (ov > mv || (ov == mv && oi < mi)) { mv = ov; mi = oi; }
        }
        if (lane == 0) ridx[win * 4 + sel] = mi;
        if (lane == mi) v = -INFINITY;
    }
}

// ---------------- Kernel 4: gathered attention, MFMA 16x16x16 bf16 ----------
// grid = (NP, 4), block = 256 = 4 waves. wave -> head = 2*by + (wid>>1),
// qhalf = wid&1 (32 q-rows as 2 qgroups of 16).
// Swapped ops both sides: S^T = K·Q^T, O^T = V^T·P^T. For the square 16x16x16
// shape, QK's D layout (col=lane&15=qrow, row=4*lg+reg=key) EQUALS PV's B-frag
// layout (col=lane&15=qrow, k=4*lg+i=key) -> P chains entirely in registers.
// exp input clamped: fminf(s,30) maps even NaN to finite -> output provably
// finite; inactive for real scores (|s|<~4).
__global__ __launch_bounds__(256) void k_attn(const float* __restrict__ proj,
    const int* __restrict__ ridx, float* __restrict__ obuf)
{
    const int win = blockIdx.x, hp = blockIdx.y;
    const int n = win / P2;
    const int tid = threadIdx.x;
    const int wid = tid >> 6, lane = tid & 63;
    const int h = hp * 2 + (wid >> 1);
    const int qbase = (wid & 1) * 32;
    const int lg = lane >> 4, d = lane & 15;

    const float* kvb[4];
    #pragma unroll
    for (int c = 0; c < 4; ++c)
        kvb[c] = proj + (size_t)((n * P2 + ridx[win * 4 + c]) * 64) * PROJC;

    // Q B-frags: col=lane&15 -> qrow (within qgroup), k=4*lg+i -> head dim
    v4s qf[2];
    #pragma unroll
    for (int g = 0; g < 2; ++g) {
        const float4 a = *(const float4*)&proj[((size_t)win * 64 + qbase + g * 16 + d) * PROJC + h * 16 + lg * 4];
        qf[g] = mk4(a.x * SCALE, a.y * SCALE, a.z * SCALE, a.w * SCALE);
    }

    f4 oacc[2] = {{0.f,0.f,0.f,0.f},{0.f,0.f,0.f,0.f}};
    float lsum[2] = {0.f, 0.f};

    #pragma unroll
    for (int c4 = 0; c4 < 4; ++c4) {            // compile-time kvb index
        const float* base = kvb[c4];
        #pragma unroll
        for (int hf = 0; hf < 2; ++hf) {        // 32 keys per half
            const int k0 = hf * 32;
            // V^T A-frags: row=lane&15 -> d, k=4*lg+i -> key
            float vv[2][4];
            #pragma unroll
            for (int t = 0; t < 2; ++t)
                #pragma unroll
                for (int i = 0; i < 4; ++i)
                    vv[t][i] = base[(size_t)(k0 + t * 16 + lg * 4 + i) * PROJC + 256 + h * 16 + d];
            // K A-frags: row=lane&15 -> key, k=4*lg+i -> head dim
            v4s kf[2];
            #pragma unroll
            for (int t = 0; t < 2; ++t) {
                const float4 a = *(const float4*)&base[(size_t)(k0 + t * 16 + d) * PROJC + 128 + h * 16 + lg * 4];
                kf[t] = mk4(a.x, a.y, a.z, a.w);
            }
            #pragma unroll
            for (int t = 0; t < 2; ++t) {
                const v4s vf = mk4(vv[t][0], vv[t][1], vv[t][2], vv[t][3]);
                #pragma unroll
                for (int g = 0; g < 2; ++g) {
                    const f4 s = MFMA16(kf[t], qf[g], ((f4){0.f,0.f,0.f,0.f}));
                    const float p0 = __expf(fminf(s.x, 30.f));
                    const float p1 = __expf(fminf(s.y, 30.f));
                    const float p2 = __expf(fminf(s.z, 30.f));
                    const float p3 = __expf(fminf(s.w, 30.f));
                    lsum[g] += (p0 + p1) + (p2 + p3);
                    const v4s pf = mk4(p0, p1, p2, p3);
                    oacc[g] = MFMA16(vf, pf, oacc[g]);
                }
            }
        }
    }
    // epilogue: qrow q lives in lanes {q, q+16, q+32, q+48} -> coset reduce
    #pragma unroll
    for (int g = 0; g < 2; ++g) {
        float ls = lsum[g];
        ls += __shfl_xor(ls, 16);
        ls += __shfl_xor(ls, 32);
        const float inv = 1.f / ls;
        float4 o = make_float4(oacc[g].x * inv, oacc[g].y * inv,
                               oacc[g].z * inv, oacc[g].w * inv);
        *(float4*)&obuf[((size_t)win * 64 + qbase + g * 16 + d) * 128 + h * 16 + lg * 4] = o;
    }
}

// ---------------- Kernel 5a: branchless lepe stencil, obuf += lepe ----------
__global__ __launch_bounds__(256) void k_lepe(const float* __restrict__ proj,
    const float* __restrict__ lw, const float* __restrict__ lb,
    float* __restrict__ obuf)
{
    const int n = blockIdx.y;
    const int ht = blockIdx.x / 28, wt = blockIdx.x % 28;
    const int tid = threadIdx.x;
    const int c = tid & 127, wi = tid >> 7;
    const int h0 = ht * 4;
    const int w = wt * 2 + wi;

    float lw9[9];
    #pragma unroll
    for (int t = 0; t < 9; ++t) lw9[t] = lw[c * 9 + t];
    const float bias = lb[c];

    int wcl[3]; bool wv[3];
    #pragma unroll
    for (int kx = 0; kx < 3; ++kx) {
        const int wc = w + kx - 1;
        wv[kx] = (wc >= 0) && (wc < HH);
        wcl[kx] = min(max(wc, 0), HH - 1);
    }
    bool rv[6]; int rcl[6];
    #pragma unroll
    for (int r = 0; r < 6; ++r) {
        const int hr = h0 + r - 1;
        rv[r] = (hr >= 0) && (hr < HH);
        rcl[r] = min(max(hr, 0), HH - 1);
    }
    float val[6][3];
    #pragma unroll
    for (int r = 0; r < 6; ++r) {
        #pragma unroll
        for (int kx = 0; kx < 3; ++kx) {
            const int hr = rcl[r], wc = wcl[kx];
            const int pp = (hr >> 3) * NWIN + (wc >> 3);
            const int t2 = (hr & 7) * 8 + (wc & 7);
            val[r][kx] = proj[((size_t)(n * P2 + pp) * 64 + t2) * PROJC + 256 + c];
        }
    }
    #pragma unroll
    for (int hi = 0; hi < 4; ++hi) {
        float a = bias;
        #pragma unroll
        for (int ky = 0; ky < 3; ++ky) {
            #pragma unroll
            for (int kx = 0; kx < 3; ++kx) {
                const float wgt = (rv[hi + ky] && wv[kx]) ? lw9[ky * 3 + kx] : 0.f;
                a = fmaf(val[hi + ky][kx], wgt, a);
            }
        }
        const int h = h0 + hi;
        const int win = (h >> 3) * NWIN + (w >> 3);
        const int t = (h & 7) * 8 + (w & 7);
        const size_t idx = (((size_t)n * P2 + win) * 64 + t) * 128 + c;
        obuf[idx] += a;
    }
}

// ---------------- Kernel 5b: pure output GEMM ----------------
__global__ __launch_bounds__(256) void k_out(const float* __restrict__ obuf,
    const float* __restrict__ Wo, const float* __restrict__ bo,
    float* __restrict__ out)
{
    const int win = blockIdx.x, jh = blockIdx.y;
    const int n = win / P2, p = win % P2;
    const int wy = p / NWIN, wx = p % NWIN;
    __shared__ __align__(16) float sA[64 * 36];
    __shared__ __align__(16) float sW[32 * 68];
    const int tid = threadIdx.x;
    const int t0 = (tid >> 4) * 4, j0 = (tid & 15) * 4;

    float acc[4][4];
    #pragma unroll
    for (int jx = 0; jx < 4; ++jx) {
        const float bb = bo[jh * 64 + j0 + jx];
        #pragma unroll
        for (int ti = 0; ti < 4; ++ti) acc[ti][jx] = bb;
    }
    for (int kc = 0; kc < 4; ++kc) {
        {
            #pragma unroll
            for (int i = tid; i < 512; i += 256) {
                const int t = i >> 3, c4 = i & 7;
                const float4 v = *(const float4*)&obuf[((size_t)win * 64 + t) * 128 + kc * 32 + c4 * 4];
                *(float4*)&sA[t * 36 + c4 * 4] = v;
            }
            #pragma unroll
            for (int i = tid; i < 2048; i += 256) {
                const int k = i >> 6, j = i & 63;
                sW[k * 68 + j] = Wo[(size_t)(kc * 32 + k) * 128 + jh * 64 + j];
            }
        }
        __syncthreads();
        #pragma unroll
        for (int k = 0; k < 32; ++k) {
            const float4 w4 = *(const float4*)&sW[k * 68 + j0];
            const float wv[4] = {w4.x, w4.y, w4.z, w4.w};
            float av[4];
            #pragma unroll
            for (int ti = 0; ti < 4; ++ti) av[ti] = sA[(t0 + ti) * 36 + k];
            #pragma unroll
            for (int ti = 0; ti < 4; ++ti)
                #pragma unroll
                for (int jx = 0; jx < 4; ++jx)
                    acc[ti][jx] = fmaf(av[ti], wv[jx], acc[ti][jx]);
        }
        __syncthreads();
    }
    const int iy = t0 >> 3, ix0 = t0 & 7;
    const int h = wy * 8 + iy, w0 = wx * 8 + ix0;
    #pragma unroll
    for (int jx = 0; jx < 4; ++jx) {
        const int cout = jh * 64 + j0 + jx;
        float4 v = make_float4(acc[0][jx], acc[1][jx], acc[2][jx], acc[3][jx]);
        *(float4*)&out[(((size_t)n * CDIM + cout) * HH + h) * HH + w0] = v;
    }
}

extern "C" void kernel_launch(void* const* d_in, const int* in_sizes, int n_in,
                              void* d_out, int out_size, void* d_ws, size_t ws_size,
                              hipStream_t stream)
{
    const float* x    = (const float*)d_in[0];
    const float* Wqkv = (const float*)d_in[1];
    const float* bqkv = (const float*)d_in[2];
    const float* lw   = (const float*)d_in[3];
    const float* lb   = (const float*)d_in[4];
    const float* Wo   = (const float*)d_in[5];
    const float* bo   = (const float*)d_in[6];
    float* out = (float*)d_out;

    float* ws   = (float*)d_ws;
    float* proj = ws;                                   // NP*64*384
    float* qwin = proj + (size_t)NP * 64 * PROJC;       // NP*128
    float* kwin = qwin + (size_t)NP * 128;              // NP*128
    int*   ridx = (int*)(kwin + (size_t)NP * 128);      // NP*4 ints
    float* obuf = (float*)(ridx + NP * 4);              // NP*64*128

    k_qkv  <<<dim3(NP * 6), 256, 0, stream>>>(x, Wqkv, bqkv, proj);
    k_means<<<dim3(NP), 128, 0, stream>>>(proj, qwin, kwin);
    k_route<<<dim3(NP), 64, 0, stream>>>(qwin, kwin, ridx);
    k_attn <<<dim3(NP, 4), 256, 0, stream>>>(proj, ridx, obuf);
    k_lepe <<<dim3(392, NB), 256, 0, stream>>>(proj, lw, lb, obuf);
    k_out  <<<dim3(NP, 2), 256, 0, stream>>>(obuf, Wo, bo, out);
}

// Round 6
// 112.746 us; speedup vs baseline: 3.0470x; 1.1943x over previous
//
#include <hip/hip_runtime.h>
#include <math.h>

#define NWIN 7
#define P2 49
#define NB 8
#define NP 392          // NB*P2
#define CDIM 128
#define HH 56
#define PROJC 384
#define HEADS 8
#define HD 16
#define TOPK 4
#define SCALE 0.08838834764831843f   // 128^-0.5

typedef __attribute__((ext_vector_type(4))) float f4;
typedef __attribute__((ext_vector_type(4))) short v4s;

// gfx950 v_mfma_f32_16x16x16_bf16 (A/B = 2 VGPRs = 4 bf16), CDNA2-lineage name.
// Fragment mappings HW-validated by the passing round-5 k_attn:
//   A[row][k]: row=lane&15, k=4*(lane>>4)+i ; B[k][col]: col=lane&15, same k
//   D[row][col]: col=lane&15, row=4*(lane>>4)+reg
#define MFMA16(a,b,c) __builtin_amdgcn_mfma_f32_16x16x16bf16_1k(a,b,c,0,0,0)

// float -> bf16 RNE via integer ops (no inline asm).
__device__ inline short f2bf(float x) {
    union { float f; unsigned u; } v; v.f = x;
    const unsigned r = v.u + 0x7FFFu + ((v.u >> 16) & 1u);
    return (short)(r >> 16);
}
__device__ inline float bf2f(short h) {
    union { unsigned u; float f; } v;
    v.u = ((unsigned)(unsigned short)h) << 16;
    return v.f;
}
__device__ inline v4s mk4(float a, float b, float c, float d) {
    v4s r;
    r[0] = f2bf(a); r[1] = f2bf(b); r[2] = f2bf(c); r[3] = f2bf(d);
    return r;
}
// packed dword: hi bf16 in bits[15:0], lo bf16 in bits[31:16]
__device__ inline unsigned pksplit(float v) {
    const short h = f2bf(v);
    const short l = f2bf(v - bf2f(h));
    return (unsigned)(unsigned short)h | (((unsigned)(unsigned short)l) << 16);
}
__device__ inline v4s lo16x4(uint4 a) {
    v4s r;
    r[0] = (short)(a.x & 0xFFFF); r[1] = (short)(a.y & 0xFFFF);
    r[2] = (short)(a.z & 0xFFFF); r[3] = (short)(a.w & 0xFFFF);
    return r;
}
__device__ inline v4s hi16x4(uint4 a) {
    v4s r;
    r[0] = (short)(a.x >> 16); r[1] = (short)(a.y >> 16);
    r[2] = (short)(a.z >> 16); r[3] = (short)(a.w >> 16);
    return r;
}

// ---------------- Kernel 0: pre-split Wqkv into hi/lo bf16 ----------------
__global__ __launch_bounds__(256) void k_wprep(const float* __restrict__ Wqkv,
    unsigned* __restrict__ wpk)
{
    const int i = blockIdx.x * 256 + threadIdx.x;
    if (i < CDIM * PROJC) wpk[i] = pksplit(Wqkv[i]);
}

// ---------------- Kernel 1: windowed QKV projection, split-bf16 MFMA -------
// grid = NP (one window/block), block = 256 = 4 waves; wave wq owns 96 cols.
// fp32-accurate via hi/lo split (Ah*Bh + Ah*Bl + Al*Bh, fp32 accum) because
// proj feeds the routing means (top-4 selection flips under plain-bf16 noise).
// Fused epilogue: q_win/k_win column means from the accumulators.
__global__ __launch_bounds__(256) void k_qkv(const float* __restrict__ x,
    const unsigned* __restrict__ wpk, const float* __restrict__ bqkv,
    float* __restrict__ proj, float* __restrict__ qwin, float* __restrict__ kwin)
{
    const int win = blockIdx.x;
    const int n = win / P2, p = win % P2;
    const int wy = p / NWIN, wx = p % NWIN;
    __shared__ __align__(16) unsigned xs[64 * 132];   // [t][c] packed, pad 132
    const int tid = threadIdx.x;
    const int wq = tid >> 6, lane = tid & 63;
    const int d = lane & 15, lg = lane >> 4;

    for (int i = tid; i < 8192; i += 256) {
        const int c = i >> 6, t = i & 63;
        const int h = wy * 8 + (t >> 3), w = wx * 8 + (t & 7);
        xs[t * 132 + c] = pksplit(x[((size_t)(n * CDIM + c) * HH + h) * HH + w]);
    }
    __syncthreads();

    const int colbase = wq * 96;
    f4 acc[4][6];
    #pragma unroll
    for (int nn = 0; nn < 6; ++nn) {
        const float bb = bqkv[colbase + nn * 16 + d];
        #pragma unroll
        for (int m = 0; m < 4; ++m) acc[m][nn] = (f4){bb, bb, bb, bb};
    }

    for (int ks = 0; ks < 8; ++ks) {
        v4s bh[6], bl[6];
        #pragma unroll
        for (int nn = 0; nn < 6; ++nn) {
            const int col = colbase + nn * 16 + d;
            uint4 wv;
            wv.x = wpk[(size_t)(ks * 16 + lg * 4 + 0) * PROJC + col];
            wv.y = wpk[(size_t)(ks * 16 + lg * 4 + 1) * PROJC + col];
            wv.z = wpk[(size_t)(ks * 16 + lg * 4 + 2) * PROJC + col];
            wv.w = wpk[(size_t)(ks * 16 + lg * 4 + 3) * PROJC + col];
            bh[nn] = lo16x4(wv);
            bl[nn] = hi16x4(wv);
        }
        #pragma unroll
        for (int m = 0; m < 4; ++m) {
            const uint4 a = *(const uint4*)&xs[(m * 16 + d) * 132 + ks * 16 + lg * 4];
            const v4s ah = lo16x4(a), al = hi16x4(a);
            #pragma unroll
            for (int nn = 0; nn < 6; ++nn) {
                acc[m][nn] = MFMA16(ah, bh[nn], acc[m][nn]);
                acc[m][nn] = MFMA16(ah, bl[nn], acc[m][nn]);
                acc[m][nn] = MFMA16(al, bh[nn], acc[m][nn]);
            }
        }
    }

    // proj write: D row = 4*lg+reg (token within m-tile), col = d
    #pragma unroll
    for (int m = 0; m < 4; ++m)
        #pragma unroll
        for (int nn = 0; nn < 6; ++nn)
            #pragma unroll
            for (int r = 0; r < 4; ++r)
                proj[(size_t)(win * 64 + m * 16 + lg * 4 + r) * PROJC + colbase + nn * 16 + d] = acc[m][nn][r];

    // fused window means for q (cols 0..127) and k (cols 128..255)
    #pragma unroll
    for (int nn = 0; nn < 6; ++nn) {
        const int col = colbase + nn * 16 + d;
        if (col < 256) {
            f4 s = acc[0][nn] + acc[1][nn];
            s += acc[2][nn];
            s += acc[3][nn];
            float cs = (s.x + s.y) + (s.z + s.w);
            cs += __shfl_xor(cs, 16);
            cs += __shfl_xor(cs, 32);
            cs *= (1.f / 64.f);
            if (lg == 0) {
                if (col < 128) qwin[(size_t)win * 128 + col] = cs;
                else           kwin[(size_t)win * 128 + col - 128] = cs;
            }
        }
    }
}

// ---------------- Kernel 3: routing top-4 ----------------
__global__ __launch_bounds__(64) void k_route(const float* __restrict__ qwin,
    const float* __restrict__ kwin, int* __restrict__ ridx)
{
    const int win = blockIdx.x;
    const int n = win / P2;
    const int lane = threadIdx.x;
    float v = -INFINITY;
    if (lane < P2) {
        const float* qr = qwin + (size_t)win * 128;
        const float* kr = kwin + ((size_t)n * P2 + lane) * 128;
        float s = 0.f;
        for (int c = 0; c < 128; ++c) s = fmaf(qr[c], kr[c], s);
        v = s;
    }
    #pragma unroll
    for (int sel = 0; sel < TOPK; ++sel) {
        float mv = v; int mi = lane;
        #pragma unroll
        for (int off = 32; off >= 1; off >>= 1) {
            const float ov = __shfl_xor(mv, off);
            const int   oi = __shfl_xor(mi, off);
            if (ov > mv || (ov == mv && oi < mi)) { mv = ov; mi = oi; }
        }
        if (lane == 0) ridx[win * 4 + sel] = mi;
        if (lane == mi) v = -INFINITY;
    }
}

// ---------------- Kernel 4: gathered attention, MFMA 16x16x16 bf16 ----------
__global__ __launch_bounds__(256) void k_attn(const float* __restrict__ proj,
    const int* __restrict__ ridx, float* __restrict__ obuf)
{
    const int win = blockIdx.x, hp = blockIdx.y;
    const int n = win / P2;
    const int tid = threadIdx.x;
    const int wid = tid >> 6, lane = tid & 63;
    const int h = hp * 2 + (wid >> 1);
    const int qbase = (wid & 1) * 32;
    const int lg = lane >> 4, d = lane & 15;

    const float* kvb[4];
    #pragma unroll
    for (int c = 0; c < 4; ++c)
        kvb[c] = proj + (size_t)((n * P2 + ridx[win * 4 + c]) * 64) * PROJC;

    v4s qf[2];
    #pragma unroll
    for (int g = 0; g < 2; ++g) {
        const float4 a = *(const float4*)&proj[((size_t)win * 64 + qbase + g * 16 + d) * PROJC + h * 16 + lg * 4];
        qf[g] = mk4(a.x * SCALE, a.y * SCALE, a.z * SCALE, a.w * SCALE);
    }

    f4 oacc[2] = {{0.f,0.f,0.f,0.f},{0.f,0.f,0.f,0.f}};
    float lsum[2] = {0.f, 0.f};

    #pragma unroll
    for (int c4 = 0; c4 < 4; ++c4) {
        const float* base = kvb[c4];
        #pragma unroll
        for (int hf = 0; hf < 2; ++hf) {
            const int k0 = hf * 32;
            float vv[2][4];
            #pragma unroll
            for (int t = 0; t < 2; ++t)
                #pragma unroll
                for (int i = 0; i < 4; ++i)
                    vv[t][i] = base[(size_t)(k0 + t * 16 + lg * 4 + i) * PROJC + 256 + h * 16 + d];
            v4s kf[2];
            #pragma unroll
            for (int t = 0; t < 2; ++t) {
                const float4 a = *(const float4*)&base[(size_t)(k0 + t * 16 + d) * PROJC + 128 + h * 16 + lg * 4];
                kf[t] = mk4(a.x, a.y, a.z, a.w);
            }
            #pragma unroll
            for (int t = 0; t < 2; ++t) {
                const v4s vf = mk4(vv[t][0], vv[t][1], vv[t][2], vv[t][3]);
                #pragma unroll
                for (int g = 0; g < 2; ++g) {
                    const f4 s = MFMA16(kf[t], qf[g], ((f4){0.f,0.f,0.f,0.f}));
                    const float p0 = __expf(fminf(s.x, 30.f));
                    const float p1 = __expf(fminf(s.y, 30.f));
                    const float p2 = __expf(fminf(s.z, 30.f));
                    const float p3 = __expf(fminf(s.w, 30.f));
                    lsum[g] += (p0 + p1) + (p2 + p3);
                    const v4s pf = mk4(p0, p1, p2, p3);
                    oacc[g] = MFMA16(vf, pf, oacc[g]);
                }
            }
        }
    }
    #pragma unroll
    for (int g = 0; g < 2; ++g) {
        float ls = lsum[g];
        ls += __shfl_xor(ls, 16);
        ls += __shfl_xor(ls, 32);
        const float inv = 1.f / ls;
        float4 o = make_float4(oacc[g].x * inv, oacc[g].y * inv,
                               oacc[g].z * inv, oacc[g].w * inv);
        *(float4*)&obuf[((size_t)win * 64 + qbase + g * 16 + d) * 128 + h * 16 + lg * 4] = o;
    }
}

// ---------------- Kernel 5a: branchless lepe stencil, obuf += lepe ----------
__global__ __launch_bounds__(256) void k_lepe(const float* __restrict__ proj,
    const float* __restrict__ lw, const float* __restrict__ lb,
    float* __restrict__ obuf)
{
    const int n = blockIdx.y;
    const int ht = blockIdx.x / 28, wt = blockIdx.x % 28;
    const int tid = threadIdx.x;
    const int c = tid & 127, wi = tid >> 7;
    const int h0 = ht * 4;
    const int w = wt * 2 + wi;

    float lw9[9];
    #pragma unroll
    for (int t = 0; t < 9; ++t) lw9[t] = lw[c * 9 + t];
    const float bias = lb[c];

    int wcl[3]; bool wv[3];
    #pragma unroll
    for (int kx = 0; kx < 3; ++kx) {
        const int wc = w + kx - 1;
        wv[kx] = (wc >= 0) && (wc < HH);
        wcl[kx] = min(max(wc, 0), HH - 1);
    }
    bool rv[6]; int rcl[6];
    #pragma unroll
    for (int r = 0; r < 6; ++r) {
        const int hr = h0 + r - 1;
        rv[r] = (hr >= 0) && (hr < HH);
        rcl[r] = min(max(hr, 0), HH - 1);
    }
    float val[6][3];
    #pragma unroll
    for (int r = 0; r < 6; ++r) {
        #pragma unroll
        for (int kx = 0; kx < 3; ++kx) {
            const int hr = rcl[r], wc = wcl[kx];
            const int pp = (hr >> 3) * NWIN + (wc >> 3);
            const int t2 = (hr & 7) * 8 + (wc & 7);
            val[r][kx] = proj[((size_t)(n * P2 + pp) * 64 + t2) * PROJC + 256 + c];
        }
    }
    #pragma unroll
    for (int hi = 0; hi < 4; ++hi) {
        float a = bias;
        #pragma unroll
        for (int ky = 0; ky < 3; ++ky) {
            #pragma unroll
            for (int kx = 0; kx < 3; ++kx) {
                const float wgt = (rv[hi + ky] && wv[kx]) ? lw9[ky * 3 + kx] : 0.f;
                a = fmaf(val[hi + ky][kx], wgt, a);
            }
        }
        const int h = h0 + hi;
        const int win = (h >> 3) * NWIN + (w >> 3);
        const int t = (h & 7) * 8 + (w & 7);
        const size_t idx = (((size_t)n * P2 + win) * 64 + t) * 128 + c;
        obuf[idx] += a;
    }
}

// ---------------- Kernel 5b: pure output GEMM ----------------
__global__ __launch_bounds__(256) void k_out(const float* __restrict__ obuf,
    const float* __restrict__ Wo, const float* __restrict__ bo,
    float* __restrict__ out)
{
    const int win = blockIdx.x, jh = blockIdx.y;
    const int n = win / P2, p = win % P2;
    const int wy = p / NWIN, wx = p % NWIN;
    __shared__ __align__(16) float sA[64 * 36];
    __shared__ __align__(16) float sW[32 * 68];
    const int tid = threadIdx.x;
    const int t0 = (tid >> 4) * 4, j0 = (tid & 15) * 4;

    float acc[4][4];
    #pragma unroll
    for (int jx = 0; jx < 4; ++jx) {
        const float bb = bo[jh * 64 + j0 + jx];
        #pragma unroll
        for (int ti = 0; ti < 4; ++ti) acc[ti][jx] = bb;
    }
    for (int kc = 0; kc < 4; ++kc) {
        {
            #pragma unroll
            for (int i = tid; i < 512; i += 256) {
                const int t = i >> 3, c4 = i & 7;
                const float4 v = *(const float4*)&obuf[((size_t)win * 64 + t) * 128 + kc * 32 + c4 * 4];
                *(float4*)&sA[t * 36 + c4 * 4] = v;
            }
            #pragma unroll
            for (int i = tid; i < 2048; i += 256) {
                const int k = i >> 6, j = i & 63;
                sW[k * 68 + j] = Wo[(size_t)(kc * 32 + k) * 128 + jh * 64 + j];
            }
        }
        __syncthreads();
        #pragma unroll
        for (int k = 0; k < 32; ++k) {
            const float4 w4 = *(const float4*)&sW[k * 68 + j0];
            const float wv[4] = {w4.x, w4.y, w4.z, w4.w};
            float av[4];
            #pragma unroll
            for (int ti = 0; ti < 4; ++ti) av[ti] = sA[(t0 + ti) * 36 + k];
            #pragma unroll
            for (int ti = 0; ti < 4; ++ti)
                #pragma unroll
                for (int jx = 0; jx < 4; ++jx)
                    acc[ti][jx] = fmaf(av[ti], wv[jx], acc[ti][jx]);
        }
        __syncthreads();
    }
    const int iy = t0 >> 3, ix0 = t0 & 7;
    const int h = wy * 8 + iy, w0 = wx * 8 + ix0;
    #pragma unroll
    for (int jx = 0; jx < 4; ++jx) {
        const int cout = jh * 64 + j0 + jx;
        float4 v = make_float4(acc[0][jx], acc[1][jx], acc[2][jx], acc[3][jx]);
        *(float4*)&out[(((size_t)n * CDIM + cout) * HH + h) * HH + w0] = v;
    }
}

extern "C" void kernel_launch(void* const* d_in, const int* in_sizes, int n_in,
                              void* d_out, int out_size, void* d_ws, size_t ws_size,
                              hipStream_t stream)
{
    const float* x    = (const float*)d_in[0];
    const float* Wqkv = (const float*)d_in[1];
    const float* bqkv = (const float*)d_in[2];
    const float* lw   = (const float*)d_in[3];
    const float* lb   = (const float*)d_in[4];
    const float* Wo   = (const float*)d_in[5];
    const float* bo   = (const float*)d_in[6];
    float* out = (float*)d_out;

    float* ws   = (float*)d_ws;
    float* proj = ws;                                   // NP*64*384
    float* qwin = proj + (size_t)NP * 64 * PROJC;       // NP*128
    float* kwin = qwin + (size_t)NP * 128;              // NP*128
    int*   ridx = (int*)(kwin + (size_t)NP * 128);      // NP*4 ints
    float* obuf = (float*)(ridx + NP * 4);              // NP*64*128
    unsigned* wpk = (unsigned*)(obuf + (size_t)NP * 64 * 128);  // 128*384 dwords

    k_wprep<<<dim3((CDIM * PROJC + 255) / 256), 256, 0, stream>>>(Wqkv, wpk);
    k_qkv  <<<dim3(NP), 256, 0, stream>>>(x, wpk, bqkv, proj, qwin, kwin);
    k_route<<<dim3(NP), 64, 0, stream>>>(qwin, kwin, ridx);
    k_attn <<<dim3(NP, 4), 256, 0, stream>>>(proj, ridx, obuf);
    k_lepe <<<dim3(392, NB), 256, 0, stream>>>(proj, lw, lb, obuf);
    k_out  <<<dim3(NP, 2), 256, 0, stream>>>(obuf, Wo, bo, out);
}

// Round 7
// 111.771 us; speedup vs baseline: 3.0736x; 1.0087x over previous
//
#include <hip/hip_runtime.h>
#include <math.h>

#define NWIN 7
#define P2 49
#define NB 8
#define NP 392          // NB*P2
#define CDIM 128
#define HH 56
#define PROJC 384
#define HEADS 8
#define HD 16
#define TOPK 4
#define SCALE 0.08838834764831843f   // 128^-0.5

typedef __attribute__((ext_vector_type(4))) float f4;
typedef __attribute__((ext_vector_type(4))) short v4s;
typedef unsigned long long u64;

// gfx950 v_mfma_f32_16x16x16_bf16; fragment maps HW-validated (rounds 5/6):
//   A[row][k]: row=lane&15, k=4*(lane>>4)+i ; B[k][col]: col=lane&15, same k
//   D[row][col]: col=lane&15, row=4*(lane>>4)+reg
#define MFMA16(a,b,c) __builtin_amdgcn_mfma_f32_16x16x16bf16_1k(a,b,c,0,0,0)

__device__ inline unsigned short f2bf(float x) {
    union { float f; unsigned u; } v; v.f = x;
    const unsigned r = v.u + 0x7FFFu + ((v.u >> 16) & 1u);
    return (unsigned short)(r >> 16);
}
__device__ inline float bf2f(unsigned short h) {
    union { unsigned u; float f; } v;
    v.u = ((unsigned)h) << 16;
    return v.f;
}
union u64frag { u64 u; v4s s; };

// ---------------- Kernel 0: pack Wqkv into bf16 B-fragment layout ----------
// wbl[(ks*24 + jt)*64 + lane] = 4 bf16 of W[ks*16+lg*4+i][jt*16+d], i=0..3
__global__ __launch_bounds__(256) void k_wprep(const float* __restrict__ Wqkv,
    u64* __restrict__ wbl)
{
    const int e = blockIdx.x * 256 + threadIdx.x;
    if (e >= 8 * 24 * 64) return;
    const int ks = e / (24 * 64);
    const int jt = (e >> 6) % 24;
    const int lane = e & 63;
    const int lg = lane >> 4, d = lane & 15;
    const int col = jt * 16 + d;
    const int k0 = ks * 16 + lg * 4;
    u64 pk = 0;
    #pragma unroll
    for (int i = 0; i < 4; ++i)
        pk |= ((u64)f2bf(Wqkv[(size_t)(k0 + i) * PROJC + col])) << (16 * i);
    wbl[e] = pk;
}

// ---------------- Kernel A: per-window channel means of x (fp32) ----------
// grid = NP, block = 256. Wave lanes = 64 tokens of one channel -> shfl reduce.
__global__ __launch_bounds__(256) void k_xmean(const float* __restrict__ x,
    float* __restrict__ xmean)
{
    const int win = blockIdx.x;
    const int n = win / P2, p = win % P2;
    const int wy = p / NWIN, wx = p % NWIN;
    const int tid = threadIdx.x;
    for (int i = tid; i < 8192; i += 256) {
        const int c = i >> 6, t = i & 63;
        const int h = wy * 8 + (t >> 3), w = wx * 8 + (t & 7);
        float v = x[(size_t)(n * CDIM + c) * 3136 + h * 56 + w];
        v += __shfl_xor(v, 1);  v += __shfl_xor(v, 2);
        v += __shfl_xor(v, 4);  v += __shfl_xor(v, 8);
        v += __shfl_xor(v, 16); v += __shfl_xor(v, 32);
        if ((tid & 63) == 0) xmean[(size_t)win * CDIM + c] = v * (1.f / 64.f);
    }
}

// ---------------- Kernel B: qwin/kwin = xmean @ Wqkv[:, :256] + b (fp32) ----
// Mean commutes with the linear projection -> routing gets exact fp32 means.
__global__ __launch_bounds__(256) void k_winproj(const float* __restrict__ xmean,
    const float* __restrict__ Wqkv, const float* __restrict__ bqkv,
    float* __restrict__ qwin, float* __restrict__ kwin)
{
    const int win = blockIdx.x;
    const int j = threadIdx.x;
    __shared__ float xm[CDIM];
    if (j < CDIM) xm[j] = xmean[(size_t)win * CDIM + j];
    __syncthreads();
    float s = bqkv[j];
    #pragma unroll 8
    for (int c = 0; c < CDIM; ++c) s = fmaf(xm[c], Wqkv[(size_t)c * PROJC + j], s);
    if (j < 128) qwin[(size_t)win * 128 + j] = s;
    else         kwin[(size_t)win * 128 + j - 128] = s;
}

// ---------------- Kernel C: routing top-4 ----------------
__global__ __launch_bounds__(64) void k_route(const float* __restrict__ qwin,
    const float* __restrict__ kwin, int* __restrict__ ridx)
{
    const int win = blockIdx.x;
    const int n = win / P2;
    const int lane = threadIdx.x;
    float v = -INFINITY;
    if (lane < P2) {
        const float* qr = qwin + (size_t)win * 128;
        const float* kr = kwin + ((size_t)n * P2 + lane) * 128;
        float s = 0.f;
        for (int c = 0; c < 128; ++c) s = fmaf(qr[c], kr[c], s);
        v = s;
    }
    #pragma unroll
    for (int sel = 0; sel < TOPK; ++sel) {
        float mv = v; int mi = lane;
        #pragma unroll
        for (int off = 32; off >= 1; off >>= 1) {
            const float ov = __shfl_xor(mv, off);
            const int   oi = __shfl_xor(mi, off);
            if (ov > mv || (ov == mv && oi < mi)) { mv = ov; mi = oi; }
        }
        if (lane == 0) ridx[win * 4 + sel] = mi;
        if (lane == mi) v = -INFINITY;
    }
}

// ---------------- Kernel 1: QKV projection, plain bf16 MFMA ----------------
// grid = (NP, 2): col-halves of 192. block = 256 = 4 waves; wave = 48 cols.
// x staged in LDS as PACKED A-fragments (u64/lane, conflict-free ds_read_b64);
// B-frags loaded from wbl (coalesced 512B per fragment tile). proj stored bf16.
__global__ __launch_bounds__(256) void k_qkv(const float* __restrict__ x,
    const u64* __restrict__ wbl, const float* __restrict__ bqkv,
    unsigned short* __restrict__ proj)
{
    const int win = blockIdx.x, ch = blockIdx.y;
    const int n = win / P2, p = win % P2;
    const int wy = p / NWIN, wx = p % NWIN;
    __shared__ u64 afl[2048];          // [ks][m][lane] packed A-frags, 16KB
    const int tid = threadIdx.x;
    const int wq = tid >> 6, lane = tid & 63;
    const int lg = lane >> 4, d = lane & 15;

    // stage: 8 u64 entries per thread, 4 x-loads each
    for (int j = tid; j < 2048; j += 256) {
        const int ks = j >> 8, m = (j >> 6) & 3, le = j & 63;
        const int lge = le >> 4, de = le & 15;
        const int c0 = ks * 16 + lge * 4;
        const int t = m * 16 + de;
        const int h = wy * 8 + (t >> 3), w = wx * 8 + (t & 7);
        const size_t xb = (size_t)(n * CDIM + c0) * 3136 + h * 56 + w;
        u64 pk = 0;
        #pragma unroll
        for (int i = 0; i < 4; ++i)
            pk |= ((u64)f2bf(x[xb + (size_t)i * 3136])) << (16 * i);
        afl[j] = pk;
    }
    __syncthreads();

    const int colbase = ch * 192 + wq * 48;
    const int jtb = ch * 12 + wq * 3;
    f4 acc[4][3];
    #pragma unroll
    for (int nn = 0; nn < 3; ++nn) {
        const float bb = bqkv[colbase + nn * 16 + d];
        #pragma unroll
        for (int m = 0; m < 4; ++m) acc[m][nn] = (f4){bb, bb, bb, bb};
    }

    #pragma unroll 2
    for (int ks = 0; ks < 8; ++ks) {
        u64frag bu[3], au[4];
        #pragma unroll
        for (int nn = 0; nn < 3; ++nn)
            bu[nn].u = wbl[(size_t)((ks * 24 + jtb + nn) * 64 + lane)];
        #pragma unroll
        for (int m = 0; m < 4; ++m)
            au[m].u = afl[(ks * 4 + m) * 64 + lane];
        #pragma unroll
        for (int m = 0; m < 4; ++m)
            #pragma unroll
            for (int nn = 0; nn < 3; ++nn)
                acc[m][nn] = MFMA16(au[m].s, bu[nn].s, acc[m][nn]);
    }

    // store bf16: D row = m*16 + lg*4 + r, col = colbase + nn*16 + d
    #pragma unroll
    for (int m = 0; m < 4; ++m)
        #pragma unroll
        for (int nn = 0; nn < 3; ++nn)
            #pragma unroll
            for (int r = 0; r < 4; ++r)
                proj[(size_t)(win * 64 + m * 16 + lg * 4 + r) * PROJC + colbase + nn * 16 + d]
                    = f2bf(acc[m][nn][r]);
}

// ---------------- Kernel 4: gathered attention (proj is bf16 now) ----------
__global__ __launch_bounds__(256) void k_attn(const unsigned short* __restrict__ proj,
    const int* __restrict__ ridx, float* __restrict__ obuf)
{
    const int win = blockIdx.x, hp = blockIdx.y;
    const int n = win / P2;
    const int tid = threadIdx.x;
    const int wid = tid >> 6, lane = tid & 63;
    const int h = hp * 2 + (wid >> 1);
    const int qbase = (wid & 1) * 32;
    const int lg = lane >> 4, d = lane & 15;

    const unsigned short* kvb[4];
    #pragma unroll
    for (int c = 0; c < 4; ++c)
        kvb[c] = proj + (size_t)((n * P2 + ridx[win * 4 + c]) * 64) * PROJC;

    v4s qf[2];
    #pragma unroll
    for (int g = 0; g < 2; ++g)
        qf[g] = *(const v4s*)&proj[((size_t)win * 64 + qbase + g * 16 + d) * PROJC + h * 16 + lg * 4];

    f4 oacc[2] = {{0.f,0.f,0.f,0.f},{0.f,0.f,0.f,0.f}};
    float lsum[2] = {0.f, 0.f};

    #pragma unroll
    for (int c4 = 0; c4 < 4; ++c4) {
        const unsigned short* base = kvb[c4];
        #pragma unroll
        for (int hf = 0; hf < 2; ++hf) {
            const int k0 = hf * 32;
            v4s vf[2];
            #pragma unroll
            for (int t = 0; t < 2; ++t)
                #pragma unroll
                for (int i = 0; i < 4; ++i)
                    vf[t][i] = (short)base[(size_t)(k0 + t * 16 + lg * 4 + i) * PROJC + 256 + h * 16 + d];
            v4s kf[2];
            #pragma unroll
            for (int t = 0; t < 2; ++t)
                kf[t] = *(const v4s*)&base[(size_t)(k0 + t * 16 + d) * PROJC + 128 + h * 16 + lg * 4];
            #pragma unroll
            for (int t = 0; t < 2; ++t) {
                #pragma unroll
                for (int g = 0; g < 2; ++g) {
                    const f4 s = MFMA16(kf[t], qf[g], ((f4){0.f,0.f,0.f,0.f}));
                    const float p0 = __expf(fminf(s.x * SCALE, 30.f));
                    const float p1 = __expf(fminf(s.y * SCALE, 30.f));
                    const float p2 = __expf(fminf(s.z * SCALE, 30.f));
                    const float p3 = __expf(fminf(s.w * SCALE, 30.f));
                    lsum[g] += (p0 + p1) + (p2 + p3);
                    v4s pf;
                    pf[0] = (short)f2bf(p0); pf[1] = (short)f2bf(p1);
                    pf[2] = (short)f2bf(p2); pf[3] = (short)f2bf(p3);
                    oacc[g] = MFMA16(vf[t], pf, oacc[g]);
                }
            }
        }
    }
    #pragma unroll
    for (int g = 0; g < 2; ++g) {
        float ls = lsum[g];
        ls += __shfl_xor(ls, 16);
        ls += __shfl_xor(ls, 32);
        const float inv = 1.f / ls;
        float4 o = make_float4(oacc[g].x * inv, oacc[g].y * inv,
                               oacc[g].z * inv, oacc[g].w * inv);
        *(float4*)&obuf[((size_t)win * 64 + qbase + g * 16 + d) * 128 + h * 16 + lg * 4] = o;
    }
}

// ---------------- Kernel 5a: branchless lepe stencil, obuf += lepe ----------
__global__ __launch_bounds__(256) void k_lepe(const unsigned short* __restrict__ proj,
    const float* __restrict__ lw, const float* __restrict__ lb,
    float* __restrict__ obuf)
{
    const int n = blockIdx.y;
    const int ht = blockIdx.x / 28, wt = blockIdx.x % 28;
    const int tid = threadIdx.x;
    const int c = tid & 127, wi = tid >> 7;
    const int h0 = ht * 4;
    const int w = wt * 2 + wi;

    float lw9[9];
    #pragma unroll
    for (int t = 0; t < 9; ++t) lw9[t] = lw[c * 9 + t];
    const float bias = lb[c];

    int wcl[3]; bool wv[3];
    #pragma unroll
    for (int kx = 0; kx < 3; ++kx) {
        const int wc = w + kx - 1;
        wv[kx] = (wc >= 0) && (wc < HH);
        wcl[kx] = min(max(wc, 0), HH - 1);
    }
    bool rv[6]; int rcl[6];
    #pragma unroll
    for (int r = 0; r < 6; ++r) {
        const int hr = h0 + r - 1;
        rv[r] = (hr >= 0) && (hr < HH);
        rcl[r] = min(max(hr, 0), HH - 1);
    }
    float val[6][3];
    #pragma unroll
    for (int r = 0; r < 6; ++r) {
        #pragma unroll
        for (int kx = 0; kx < 3; ++kx) {
            const int hr = rcl[r], wc = wcl[kx];
            const int pp = (hr >> 3) * NWIN + (wc >> 3);
            const int t2 = (hr & 7) * 8 + (wc & 7);
            val[r][kx] = bf2f(proj[((size_t)(n * P2 + pp) * 64 + t2) * PROJC + 256 + c]);
        }
    }
    #pragma unroll
    for (int hi = 0; hi < 4; ++hi) {
        float a = bias;
        #pragma unroll
        for (int ky = 0; ky < 3; ++ky) {
            #pragma unroll
            for (int kx = 0; kx < 3; ++kx) {
                const float wgt = (rv[hi + ky] && wv[kx]) ? lw9[ky * 3 + kx] : 0.f;
                a = fmaf(val[hi + ky][kx], wgt, a);
            }
        }
        const int h = h0 + hi;
        const int win = (h >> 3) * NWIN + (w >> 3);
        const int t = (h & 7) * 8 + (w & 7);
        const size_t idx = (((size_t)n * P2 + win) * 64 + t) * 128 + c;
        obuf[idx] += a;
    }
}

// ---------------- Kernel 5b: pure output GEMM ----------------
__global__ __launch_bounds__(256) void k_out(const float* __restrict__ obuf,
    const float* __restrict__ Wo, const float* __restrict__ bo,
    float* __restrict__ out)
{
    const int win = blockIdx.x, jh = blockIdx.y;
    const int n = win / P2, p = win % P2;
    const int wy = p / NWIN, wx = p % NWIN;
    __shared__ __align__(16) float sA[64 * 36];
    __shared__ __align__(16) float sW[32 * 68];
    const int tid = threadIdx.x;
    const int t0 = (tid >> 4) * 4, j0 = (tid & 15) * 4;

    float acc[4][4];
    #pragma unroll
    for (int jx = 0; jx < 4; ++jx) {
        const float bb = bo[jh * 64 + j0 + jx];
        #pragma unroll
        for (int ti = 0; ti < 4; ++ti) acc[ti][jx] = bb;
    }
    for (int kc = 0; kc < 4; ++kc) {
        {
            #pragma unroll
            for (int i = tid; i < 512; i += 256) {
                const int t = i >> 3, c4 = i & 7;
                const float4 v = *(const float4*)&obuf[((size_t)win * 64 + t) * 128 + kc * 32 + c4 * 4];
                *(float4*)&sA[t * 36 + c4 * 4] = v;
            }
            #pragma unroll
            for (int i = tid; i < 2048; i += 256) {
                const int k = i >> 6, j = i & 63;
                sW[k * 68 + j] = Wo[(size_t)(kc * 32 + k) * 128 + jh * 64 + j];
            }
        }
        __syncthreads();
        #pragma unroll
        for (int k = 0; k < 32; ++k) {
            const float4 w4 = *(const float4*)&sW[k * 68 + j0];
            const float wv[4] = {w4.x, w4.y, w4.z, w4.w};
            float av[4];
            #pragma unroll
            for (int ti = 0; ti < 4; ++ti) av[ti] = sA[(t0 + ti) * 36 + k];
            #pragma unroll
            for (int ti = 0; ti < 4; ++ti)
                #pragma unroll
                for (int jx = 0; jx < 4; ++jx)
                    acc[ti][jx] = fmaf(av[ti], wv[jx], acc[ti][jx]);
        }
        __syncthreads();
    }
    const int iy = t0 >> 3, ix0 = t0 & 7;
    const int h = wy * 8 + iy, w0 = wx * 8 + ix0;
    #pragma unroll
    for (int jx = 0; jx < 4; ++jx) {
        const int cout = jh * 64 + j0 + jx;
        float4 v = make_float4(acc[0][jx], acc[1][jx], acc[2][jx], acc[3][jx]);
        *(float4*)&out[(((size_t)n * CDIM + cout) * HH + h) * HH + w0] = v;
    }
}

extern "C" void kernel_launch(void* const* d_in, const int* in_sizes, int n_in,
                              void* d_out, int out_size, void* d_ws, size_t ws_size,
                              hipStream_t stream)
{
    const float* x    = (const float*)d_in[0];
    const float* Wqkv = (const float*)d_in[1];
    const float* bqkv = (const float*)d_in[2];
    const float* lw   = (const float*)d_in[3];
    const float* lb   = (const float*)d_in[4];
    const float* Wo   = (const float*)d_in[5];
    const float* bo   = (const float*)d_in[6];
    float* out = (float*)d_out;

    char* w = (char*)d_ws;
    unsigned short* proj = (unsigned short*)w;  w += (size_t)NP * 64 * PROJC * 2;  // 19.3 MB
    float* obuf  = (float*)w;                   w += (size_t)NP * 64 * 128 * 4;    // 12.8 MB
    u64*   wbl   = (u64*)w;                     w += (size_t)8 * 24 * 64 * 8;      // 96 KB
    float* xmean = (float*)w;                   w += (size_t)NP * CDIM * 4;
    float* qwin  = (float*)w;                   w += (size_t)NP * 128 * 4;
    float* kwin  = (float*)w;                   w += (size_t)NP * 128 * 4;
    int*   ridx  = (int*)w;

    k_wprep  <<<dim3(48), 256, 0, stream>>>(Wqkv, wbl);
    k_xmean  <<<dim3(NP), 256, 0, stream>>>(x, xmean);
    k_winproj<<<dim3(NP), 256, 0, stream>>>(xmean, Wqkv, bqkv, qwin, kwin);
    k_route  <<<dim3(NP), 64, 0, stream>>>(qwin, kwin, ridx);
    k_qkv    <<<dim3(NP, 2), 256, 0, stream>>>(x, wbl, bqkv, proj);
    k_attn   <<<dim3(NP, 4), 256, 0, stream>>>(proj, ridx, obuf);
    k_lepe   <<<dim3(392, NB), 256, 0, stream>>>(proj, lw, lb, obuf);
    k_out    <<<dim3(NP, 2), 256, 0, stream>>>(obuf, Wo, bo, out);
}

// Round 8
// 94.035 us; speedup vs baseline: 3.6533x; 1.1886x over previous
//
#include <hip/hip_runtime.h>
#include <math.h>

#define NWIN 7
#define P2 49
#define NB 8
#define NP 392          // NB*P2
#define CDIM 128
#define HH 56
#define PROJC 384
#define HEADS 8
#define HD 16
#define TOPK 4
#define SCALE 0.08838834764831843f   // 128^-0.5

typedef __attribute__((ext_vector_type(4))) float f4;
typedef __attribute__((ext_vector_type(4))) short v4s;
typedef unsigned long long u64;

// gfx950 v_mfma_f32_16x16x16_bf16; fragment maps HW-validated (rounds 5-7):
//   A[row][k]: row=lane&15, k=4*(lane>>4)+i ; B[k][col]: col=lane&15, same k
//   D[row][col]: col=lane&15, row=4*(lane>>4)+reg
#define MFMA16(a,b,c) __builtin_amdgcn_mfma_f32_16x16x16bf16_1k(a,b,c,0,0,0)

__device__ inline unsigned short f2bf(float x) {
    union { float f; unsigned u; } v; v.f = x;
    const unsigned r = v.u + 0x7FFFu + ((v.u >> 16) & 1u);
    return (unsigned short)(r >> 16);
}
__device__ inline float bf2f(unsigned short h) {
    union { unsigned u; float f; } v;
    v.u = ((unsigned)h) << 16;
    return v.f;
}
union u64frag { u64 u; v4s s; };

// ---------------- Kernel 0: pack Wqkv (bf16) + Wo (hi/lo split) frags ------
// wbl[(ks*24+jt)*64+lane]  = 4 bf16 of Wqkv[ks*16+lg*4+i][jt*16+d]
// wo_hi/wo_lo[(ks*8+jt)*64+lane] = split bf16 of Wo[ks*16+lg*4+i][jt*16+d]
__global__ __launch_bounds__(256) void k_wprep(const float* __restrict__ Wqkv,
    const float* __restrict__ Wo, u64* __restrict__ wbl,
    u64* __restrict__ wo_hi, u64* __restrict__ wo_lo)
{
    const int e = blockIdx.x * 256 + threadIdx.x;
    if (e < 8 * 24 * 64) {
        const int ks = e / (24 * 64);
        const int jt = (e >> 6) % 24;
        const int lane = e & 63;
        const int lg = lane >> 4, d = lane & 15;
        const int col = jt * 16 + d;
        const int k0 = ks * 16 + lg * 4;
        u64 pk = 0;
        #pragma unroll
        for (int i = 0; i < 4; ++i)
            pk |= ((u64)f2bf(Wqkv[(size_t)(k0 + i) * PROJC + col])) << (16 * i);
        wbl[e] = pk;
    } else if (e < 8 * 24 * 64 + 8 * 8 * 64) {
        const int e2 = e - 8 * 24 * 64;
        const int ks = e2 >> 9;
        const int jt = (e2 >> 6) & 7;
        const int lane = e2 & 63;
        const int lg = lane >> 4, d = lane & 15;
        const int col = jt * 16 + d;
        const int k0 = ks * 16 + lg * 4;
        u64 ph = 0, pl = 0;
        #pragma unroll
        for (int i = 0; i < 4; ++i) {
            const float v = Wo[(size_t)(k0 + i) * CDIM + col];
            const unsigned short h = f2bf(v);
            const unsigned short l = f2bf(v - bf2f(h));
            ph |= ((u64)h) << (16 * i);
            pl |= ((u64)l) << (16 * i);
        }
        wo_hi[e2] = ph;
        wo_lo[e2] = pl;
    }
}

// ---------------- Kernel A: window means + fp32 routing projection ----------
// Mean commutes with the linear projection -> routing gets exact fp32 logits.
__global__ __launch_bounds__(256) void k_wmean(const float* __restrict__ x,
    const float* __restrict__ Wqkv, const float* __restrict__ bqkv,
    float* __restrict__ qwin, float* __restrict__ kwin)
{
    const int win = blockIdx.x;
    const int n = win / P2, p = win % P2;
    const int wy = p / NWIN, wx = p % NWIN;
    const int tid = threadIdx.x;
    __shared__ float xm[CDIM];
    for (int i = tid; i < 8192; i += 256) {
        const int c = i >> 6, t = i & 63;
        const int h = wy * 8 + (t >> 3), w = wx * 8 + (t & 7);
        float v = x[(size_t)(n * CDIM + c) * 3136 + h * HH + w];
        v += __shfl_xor(v, 1);  v += __shfl_xor(v, 2);
        v += __shfl_xor(v, 4);  v += __shfl_xor(v, 8);
        v += __shfl_xor(v, 16); v += __shfl_xor(v, 32);
        if ((tid & 63) == 0) xm[c] = v * (1.f / 64.f);
    }
    __syncthreads();
    const int j = tid;      // 0..255 -> q/k cols
    float s = bqkv[j];
    #pragma unroll 8
    for (int c = 0; c < CDIM; ++c) s = fmaf(xm[c], Wqkv[(size_t)c * PROJC + j], s);
    if (j < 128) qwin[(size_t)win * 128 + j] = s;
    else         kwin[(size_t)win * 128 + j - 128] = s;
}

// ---------------- Kernel B: routing top-4 ----------------
__global__ __launch_bounds__(64) void k_route(const float* __restrict__ qwin,
    const float* __restrict__ kwin, int* __restrict__ ridx)
{
    const int win = blockIdx.x;
    const int n = win / P2;
    const int lane = threadIdx.x;
    float v = -INFINITY;
    if (lane < P2) {
        const float* qr = qwin + (size_t)win * 128;
        const float* kr = kwin + ((size_t)n * P2 + lane) * 128;
        float s = 0.f;
        for (int c = 0; c < 128; ++c) s = fmaf(qr[c], kr[c], s);
        v = s;
    }
    #pragma unroll
    for (int sel = 0; sel < TOPK; ++sel) {
        float mv = v; int mi = lane;
        #pragma unroll
        for (int off = 32; off >= 1; off >>= 1) {
            const float ov = __shfl_xor(mv, off);
            const int   oi = __shfl_xor(mi, off);
            if (ov > mv || (ov == mv && oi < mi)) { mv = ov; mi = oi; }
        }
        if (lane == 0) ridx[win * 4 + sel] = mi;
        if (lane == mi) v = -INFINITY;
    }
}

// ---------------- Kernel 1: QKV projection, plain bf16 MFMA ----------------
__global__ __launch_bounds__(256) void k_qkv(const float* __restrict__ x,
    const u64* __restrict__ wbl, const float* __restrict__ bqkv,
    unsigned short* __restrict__ proj)
{
    const int win = blockIdx.x, ch = blockIdx.y;
    const int n = win / P2, p = win % P2;
    const int wy = p / NWIN, wx = p % NWIN;
    __shared__ u64 afl[2048];          // [ks][m][lane] packed A-frags, 16KB
    const int tid = threadIdx.x;
    const int wq = tid >> 6, lane = tid & 63;
    const int lg = lane >> 4, d = lane & 15;

    for (int j = tid; j < 2048; j += 256) {
        const int ks = j >> 8, m = (j >> 6) & 3, le = j & 63;
        const int lge = le >> 4, de = le & 15;
        const int c0 = ks * 16 + lge * 4;
        const int t = m * 16 + de;
        const int h = wy * 8 + (t >> 3), w = wx * 8 + (t & 7);
        const size_t xb = (size_t)(n * CDIM + c0) * 3136 + h * HH + w;
        u64 pk = 0;
        #pragma unroll
        for (int i = 0; i < 4; ++i)
            pk |= ((u64)f2bf(x[xb + (size_t)i * 3136])) << (16 * i);
        afl[j] = pk;
    }
    __syncthreads();

    const int colbase = ch * 192 + wq * 48;
    const int jtb = ch * 12 + wq * 3;
    f4 acc[4][3];
    #pragma unroll
    for (int nn = 0; nn < 3; ++nn) {
        const float bb = bqkv[colbase + nn * 16 + d];
        #pragma unroll
        for (int m = 0; m < 4; ++m) acc[m][nn] = (f4){bb, bb, bb, bb};
    }

    #pragma unroll 2
    for (int ks = 0; ks < 8; ++ks) {
        u64frag bu[3], au[4];
        #pragma unroll
        for (int nn = 0; nn < 3; ++nn)
            bu[nn].u = wbl[(size_t)((ks * 24 + jtb + nn) * 64 + lane)];
        #pragma unroll
        for (int m = 0; m < 4; ++m)
            au[m].u = afl[(ks * 4 + m) * 64 + lane];
        #pragma unroll
        for (int m = 0; m < 4; ++m)
            #pragma unroll
            for (int nn = 0; nn < 3; ++nn)
                acc[m][nn] = MFMA16(au[m].s, bu[nn].s, acc[m][nn]);
    }

    #pragma unroll
    for (int m = 0; m < 4; ++m)
        #pragma unroll
        for (int nn = 0; nn < 3; ++nn)
            #pragma unroll
            for (int r = 0; r < 4; ++r)
                proj[(size_t)(win * 64 + m * 16 + lg * 4 + r) * PROJC + colbase + nn * 16 + d]
                    = f2bf(acc[m][nn][r]);
}

// ---------------- Kernel 2: fused attention + lepe + output GEMM -----------
// 1 block/window, 512 thr = 8 waves = 8 heads. o-tile in LDS (no obuf).
// attn: in-register MFMA chain (as before, SCALE folded into q-frags).
// lepe: branchless 3x3 stencil accumulated into o_lds.
// out:  out^T = Wo^T(o+lepe)^T, split-bf16 MFMA (both operands hi/lo),
//       pixel-contiguous stores to NCHW.
__global__ __launch_bounds__(512) void k_tail(const unsigned short* __restrict__ proj,
    const int* __restrict__ ridx, const u64* __restrict__ wo_hi,
    const u64* __restrict__ wo_lo, const float* __restrict__ lw,
    const float* __restrict__ lb, const float* __restrict__ bo,
    float* __restrict__ out)
{
    const int win = blockIdx.x;
    const int n = win / P2, p = win % P2;
    const int wy = p / NWIN, wx = p % NWIN;
    __shared__ float o_lds[64 * 132];   // [tok][ch], pad 132 (33.8 KB)
    const int tid = threadIdx.x;
    const int w8 = tid >> 6, lane = tid & 63;
    const int lg = lane >> 4, d = lane & 15;

    // ===== Phase 1: attention (wave = head w8) =====
    {
        const int h = w8;
        const unsigned short* kvb[4];
        #pragma unroll
        for (int c = 0; c < 4; ++c)
            kvb[c] = proj + (size_t)((n * P2 + ridx[win * 4 + c]) * 64) * PROJC;

        v4s qf[4];
        #pragma unroll
        for (int g = 0; g < 4; ++g) {
            v4s q = *(const v4s*)&proj[((size_t)win * 64 + g * 16 + d) * PROJC + h * 16 + lg * 4];
            #pragma unroll
            for (int i = 0; i < 4; ++i)
                q[i] = (short)f2bf(bf2f((unsigned short)q[i]) * SCALE);
            qf[g] = q;
        }

        f4 oacc[4] = {{0.f,0.f,0.f,0.f},{0.f,0.f,0.f,0.f},{0.f,0.f,0.f,0.f},{0.f,0.f,0.f,0.f}};
        float lsum[4] = {0.f, 0.f, 0.f, 0.f};

        #pragma unroll
        for (int c4 = 0; c4 < 4; ++c4) {
            const unsigned short* base = kvb[c4];
            #pragma unroll
            for (int hf = 0; hf < 2; ++hf) {
                const int k0 = hf * 32;
                v4s vf[2];
                #pragma unroll
                for (int t = 0; t < 2; ++t)
                    #pragma unroll
                    for (int i = 0; i < 4; ++i)
                        vf[t][i] = (short)base[(size_t)(k0 + t * 16 + lg * 4 + i) * PROJC + 256 + h * 16 + d];
                v4s kf[2];
                #pragma unroll
                for (int t = 0; t < 2; ++t)
                    kf[t] = *(const v4s*)&base[(size_t)(k0 + t * 16 + d) * PROJC + 128 + h * 16 + lg * 4];
                #pragma unroll
                for (int t = 0; t < 2; ++t) {
                    #pragma unroll
                    for (int g = 0; g < 4; ++g) {
                        const f4 s = MFMA16(kf[t], qf[g], ((f4){0.f,0.f,0.f,0.f}));
                        const float p0 = __expf(s.x), p1 = __expf(s.y);
                        const float p2 = __expf(s.z), p3 = __expf(s.w);
                        lsum[g] += (p0 + p1) + (p2 + p3);
                        v4s pf;
                        pf[0] = (short)f2bf(p0); pf[1] = (short)f2bf(p1);
                        pf[2] = (short)f2bf(p2); pf[3] = (short)f2bf(p3);
                        oacc[g] = MFMA16(vf[t], pf, oacc[g]);
                    }
                }
            }
        }
        #pragma unroll
        for (int g = 0; g < 4; ++g) {
            float ls = lsum[g];
            ls += __shfl_xor(ls, 16);
            ls += __shfl_xor(ls, 32);
            const float inv = 1.f / ls;
            f4 o = oacc[g];
            o.x *= inv; o.y *= inv; o.z *= inv; o.w *= inv;
            *(f4*)&o_lds[(g * 16 + d) * 132 + h * 16 + lg * 4] = o;
        }
    }
    __syncthreads();

    // ===== Phase 2: lepe stencil, o_lds += conv3x3(v) =====
    {
        const int c = tid & 127, quad = tid >> 7;
        float lw9[9];
        #pragma unroll
        for (int t = 0; t < 9; ++t) lw9[t] = lw[c * 9 + t];
        const float bias = lb[c];
        const int r0 = quad * 2;

        bool vr[4]; int ghc[4];
        #pragma unroll
        for (int j = 0; j < 4; ++j) {
            const int gh = wy * 8 + r0 - 1 + j;
            vr[j] = (gh >= 0) && (gh < HH);
            ghc[j] = min(max(gh, 0), HH - 1);
        }
        bool vc[10]; int gwc[10];
        #pragma unroll
        for (int k = 0; k < 10; ++k) {
            const int gw = wx * 8 - 1 + k;
            vc[k] = (gw >= 0) && (gw < HH);
            gwc[k] = min(max(gw, 0), HH - 1);
        }
        float val[4][10];
        #pragma unroll
        for (int j = 0; j < 4; ++j)
            #pragma unroll
            for (int k = 0; k < 10; ++k) {
                const int pp = (ghc[j] >> 3) * NWIN + (gwc[k] >> 3);
                const int t2 = (ghc[j] & 7) * 8 + (gwc[k] & 7);
                val[j][k] = bf2f(proj[((size_t)(n * P2 + pp) * 64 + t2) * PROJC + 256 + c]);
            }
        #pragma unroll
        for (int rr = 0; rr < 2; ++rr) {
            const int iy = r0 + rr;
            #pragma unroll
            for (int ix = 0; ix < 8; ++ix) {
                float a = bias;
                #pragma unroll
                for (int ky = 0; ky < 3; ++ky)
                    #pragma unroll
                    for (int kx = 0; kx < 3; ++kx) {
                        const float wgt = (vr[rr + ky] && vc[ix + kx]) ? lw9[ky * 3 + kx] : 0.f;
                        a = fmaf(val[rr + ky][ix + kx], wgt, a);
                    }
                o_lds[(iy * 8 + ix) * 132 + c] += a;
            }
        }
    }
    __syncthreads();

    // ===== Phase 3: out^T = Wo^T (o+lepe)^T + bo, split-bf16 MFMA =====
    {
        const int jt = w8;     // wave = 16 output channels
        f4 acc[4];
        #pragma unroll
        for (int m = 0; m < 4; ++m) {
            f4 b;
            #pragma unroll
            for (int r = 0; r < 4; ++r) b[r] = bo[jt * 16 + lg * 4 + r];
            acc[m] = b;
        }
        #pragma unroll 2
        for (int ks = 0; ks < 8; ++ks) {
            u64frag ahi, alo;
            ahi.u = wo_hi[(size_t)((ks * 8 + jt) * 64 + lane)];
            alo.u = wo_lo[(size_t)((ks * 8 + jt) * 64 + lane)];
            #pragma unroll
            for (int m = 0; m < 4; ++m) {
                const f4 ov = *(const f4*)&o_lds[(m * 16 + d) * 132 + ks * 16 + lg * 4];
                v4s bh, bl;
                #pragma unroll
                for (int i = 0; i < 4; ++i) {
                    const unsigned short hh = f2bf(ov[i]);
                    bh[i] = (short)hh;
                    bl[i] = (short)f2bf(ov[i] - bf2f(hh));
                }
                acc[m] = MFMA16(ahi.s, bh, acc[m]);
                acc[m] = MFMA16(ahi.s, bl, acc[m]);
                acc[m] = MFMA16(alo.s, bh, acc[m]);
            }
        }
        #pragma unroll
        for (int m = 0; m < 4; ++m) {
            const int tok = m * 16 + d;
            const int h = wy * 8 + (tok >> 3), w = wx * 8 + (tok & 7);
            #pragma unroll
            for (int r = 0; r < 4; ++r) {
                const int oc = jt * 16 + lg * 4 + r;
                out[((size_t)(n * CDIM + oc)) * 3136 + h * HH + w] = acc[m][r];
            }
        }
    }
}

extern "C" void kernel_launch(void* const* d_in, const int* in_sizes, int n_in,
                              void* d_out, int out_size, void* d_ws, size_t ws_size,
                              hipStream_t stream)
{
    const float* x    = (const float*)d_in[0];
    const float* Wqkv = (const float*)d_in[1];
    const float* bqkv = (const float*)d_in[2];
    const float* lw   = (const float*)d_in[3];
    const float* lb   = (const float*)d_in[4];
    const float* Wo   = (const float*)d_in[5];
    const float* bo   = (const float*)d_in[6];
    float* out = (float*)d_out;

    char* w = (char*)d_ws;
    unsigned short* proj = (unsigned short*)w;  w += (size_t)NP * 64 * PROJC * 2;  // 19.3 MB
    u64*   wbl   = (u64*)w;                     w += (size_t)8 * 24 * 64 * 8;      // 96 KB
    u64*   wo_hi = (u64*)w;                     w += (size_t)8 * 8 * 64 * 8;       // 32 KB
    u64*   wo_lo = (u64*)w;                     w += (size_t)8 * 8 * 64 * 8;       // 32 KB
    float* qwin  = (float*)w;                   w += (size_t)NP * 128 * 4;
    float* kwin  = (float*)w;                   w += (size_t)NP * 128 * 4;
    int*   ridx  = (int*)w;

    k_wprep<<<dim3(64), 256, 0, stream>>>(Wqkv, Wo, wbl, wo_hi, wo_lo);
    k_wmean<<<dim3(NP), 256, 0, stream>>>(x, Wqkv, bqkv, qwin, kwin);
    k_route<<<dim3(NP), 64, 0, stream>>>(qwin, kwin, ridx);
    k_qkv  <<<dim3(NP, 2), 256, 0, stream>>>(x, wbl, bqkv, proj);
    k_tail <<<dim3(NP), 512, 0, stream>>>(proj, ridx, wo_hi, wo_lo, lw, lb, bo, out);
}